// Round 1
// baseline (713.646 us; speedup 1.0000x reference)
//
#include <hip/hip_runtime.h>
#include <hip/hip_bf16.h>

// Problem: B=4, S=4096, D=256 single-head causal attention, fp32 in/out.
// ws layout: Qb bf16 [4][4096][256] @ 0, Kb bf16 @ 8MB, Vt bf16 [4][256][4096] @ 16MB (24MB total).

#define SEQ 4096
#define DIM 256
#define NBATCH 4

typedef __attribute__((ext_vector_type(8))) short bf16x8;
typedef __attribute__((ext_vector_type(4))) float f32x4;
typedef __attribute__((ext_vector_type(4))) unsigned short us4;

static __device__ inline unsigned short f2bf(float f) {
  unsigned int u = __float_as_uint(f);
  u += 0x7FFFu + ((u >> 16) & 1u);   // RNE to bf16
  return (unsigned short)(u >> 16);
}

// ---------------- Kernel 1: QKV projection, C = X @ W^T (bf16 MFMA) -----------------
// grid (M/128, 256/64, 3), block 256 (4 waves). z: 0->Q, 1->K, 2->V (stored transposed).
__global__ __launch_bounds__(256) void qkv_gemm(
    const float* __restrict__ x, const float* __restrict__ Wq,
    const float* __restrict__ Wk, const float* __restrict__ Wv,
    unsigned short* __restrict__ qb, unsigned short* __restrict__ kb,
    unsigned short* __restrict__ vt)
{
  __shared__ unsigned short A_lds[128][40];  // 128 rows x 32 k, +8 pad (bank-conflict-free)
  __shared__ unsigned short B_lds[64][40];

  const int tid = threadIdx.x;
  const int lane = tid & 63;
  const int w = tid >> 6;
  const int lo = lane & 15, hi = lane >> 4;
  const int mb = blockIdx.x * 128;
  const int nb = blockIdx.y * 64;
  const int z = blockIdx.z;
  const float* Wm = (z == 0) ? Wq : (z == 1) ? Wk : Wv;

  f32x4 acc[2][4];
#pragma unroll
  for (int mi = 0; mi < 2; mi++)
#pragma unroll
    for (int ni = 0; ni < 4; ni++) acc[mi][ni] = (f32x4){0.f, 0.f, 0.f, 0.f};

  for (int ks = 0; ks < 8; ++ks) {
    const int k0 = ks * 32;
    __syncthreads();
    // stage A: 128x32 fp32 -> bf16 LDS (1024 float4 chunks / 256 thr)
#pragma unroll
    for (int i = 0; i < 4; ++i) {
      int f = tid + i * 256;
      int row = f >> 3, c4 = (f & 7) * 4;
      float4 v = *(const float4*)(x + (size_t)(mb + row) * DIM + k0 + c4);
      us4 bv = { f2bf(v.x), f2bf(v.y), f2bf(v.z), f2bf(v.w) };
      *(us4*)&A_lds[row][c4] = bv;
    }
    // stage B: 64x32
#pragma unroll
    for (int i = 0; i < 2; ++i) {
      int f = tid + i * 256;
      int row = f >> 3, c4 = (f & 7) * 4;
      float4 v = *(const float4*)(Wm + (size_t)(nb + row) * DIM + k0 + c4);
      us4 bv = { f2bf(v.x), f2bf(v.y), f2bf(v.z), f2bf(v.w) };
      *(us4*)&B_lds[row][c4] = bv;
    }
    __syncthreads();
    bf16x8 a[2], bfr[4];
#pragma unroll
    for (int mi = 0; mi < 2; mi++) a[mi] = *(const bf16x8*)&A_lds[w * 32 + mi * 16 + lo][hi * 8];
#pragma unroll
    for (int ni = 0; ni < 4; ni++) bfr[ni] = *(const bf16x8*)&B_lds[ni * 16 + lo][hi * 8];
#pragma unroll
    for (int mi = 0; mi < 2; mi++)
#pragma unroll
      for (int ni = 0; ni < 4; ni++)
        acc[mi][ni] = __builtin_amdgcn_mfma_f32_16x16x32_bf16(a[mi], bfr[ni], acc[mi][ni], 0, 0, 0);
  }

  if (z < 2) {
    unsigned short* dst = (z == 0) ? qb : kb;
#pragma unroll
    for (int mi = 0; mi < 2; mi++) {
      int r0 = mb + w * 32 + mi * 16 + hi * 4;
#pragma unroll
      for (int ni = 0; ni < 4; ni++) {
        int col = nb + ni * 16 + lo;
#pragma unroll
        for (int j = 0; j < 4; j++)
          dst[(size_t)(r0 + j) * DIM + col] = f2bf(acc[mi][ni][j]);
      }
    }
  } else {
    // V stored transposed: Vt[b][d][s]; 4 consecutive s per lane -> 8B stores
#pragma unroll
    for (int mi = 0; mi < 2; mi++) {
      int s0 = mb + w * 32 + mi * 16 + hi * 4;
      int bidx = s0 >> 12, sl = s0 & 4095;
#pragma unroll
      for (int ni = 0; ni < 4; ni++) {
        int col = nb + ni * 16 + lo;
        us4 pv = { f2bf(acc[mi][ni][0]), f2bf(acc[mi][ni][1]),
                   f2bf(acc[mi][ni][2]), f2bf(acc[mi][ni][3]) };
        *(us4*)(vt + (size_t)bidx * (DIM * SEQ) + (size_t)col * SEQ + sl) = pv;
      }
    }
  }
}

// ---------------- Kernel 2: causal flash attention -----------------
// grid (S/32, B), block 128 (2 waves; wave w owns q rows qbase+16w..+16).
__global__ __launch_bounds__(128) void attn(
    const unsigned short* __restrict__ qb, const unsigned short* __restrict__ kb,
    const unsigned short* __restrict__ vt, float* __restrict__ out)
{
  __shared__ unsigned short K_lds[32][264];       // 32 kv rows x 256 d, +8 pad
  __shared__ unsigned short P_lds[2][16][40];     // per-wave P tile 16q x 32kv, +8 pad

  const int tid = threadIdx.x;
  const int lane = tid & 63;
  const int w = tid >> 6;
  const int lo = lane & 15, hi = lane >> 4;
  const int qt = blockIdx.x;
  const int b = blockIdx.y;
  const int qbase = qt * 32;
  const float scale = 0.0625f;  // 1/sqrt(256)

  // Q fragments in registers (16 rows x 256 d per wave)
  bf16x8 qf[8];
  {
    const unsigned short* qrow = qb + (size_t)(b * SEQ + qbase + w * 16 + lo) * DIM;
#pragma unroll
    for (int kk = 0; kk < 8; kk++)
      qf[kk] = *(const bf16x8*)(qrow + kk * 32 + hi * 8);
  }

  float m_run[4], l_run[4];
#pragma unroll
  for (int j = 0; j < 4; j++) { m_run[j] = -__builtin_inff(); l_run[j] = 0.f; }
  f32x4 o_acc[16];
#pragma unroll
  for (int n = 0; n < 16; n++) o_acc[n] = (f32x4){0.f, 0.f, 0.f, 0.f};

  const unsigned short* vb_base = vt + (size_t)b * (DIM * SEQ);

  for (int t = 0; t <= qt; ++t) {
    __syncthreads();
    // stage K tile 32x256 bf16 (1024 16B-chunks / 128 thr)
#pragma unroll
    for (int i = 0; i < 8; ++i) {
      int c = tid + i * 128;
      int row = c >> 5, c8 = (c & 31) * 8;
      int4 v = *(const int4*)(kb + (size_t)(b * SEQ + t * 32 + row) * DIM + c8);
      *(int4*)&K_lds[row][c8] = v;
    }
    __syncthreads();

    // S = Q K^T
    f32x4 sf[2];
#pragma unroll
    for (int nf = 0; nf < 2; nf++) {
      f32x4 a = (f32x4){0.f, 0.f, 0.f, 0.f};
#pragma unroll
      for (int kk = 0; kk < 8; kk++) {
        bf16x8 kfr = *(const bf16x8*)&K_lds[nf * 16 + lo][kk * 32 + hi * 8];
        a = __builtin_amdgcn_mfma_f32_16x16x32_bf16(qf[kk], kfr, a, 0, 0, 0);
      }
      sf[nf] = a;
    }

    // scale + causal mask (diagonal tile only)
    float s[2][4];
#pragma unroll
    for (int nf = 0; nf < 2; nf++)
#pragma unroll
      for (int j = 0; j < 4; j++) {
        float v = sf[nf][j] * scale;
        if (t == qt) {
          int qg = qbase + w * 16 + hi * 4 + j;
          int kg = t * 32 + nf * 16 + lo;
          if (kg > qg) v = -__builtin_inff();
        }
        s[nf][j] = v;
      }

    // online softmax (rows live in 16-lane groups; regs j = 4 q-rows)
    float alpha[4];
#pragma unroll
    for (int j = 0; j < 4; j++) {
      float v = fmaxf(s[0][j], s[1][j]);
      v = fmaxf(v, __shfl_xor(v, 1));
      v = fmaxf(v, __shfl_xor(v, 2));
      v = fmaxf(v, __shfl_xor(v, 4));
      v = fmaxf(v, __shfl_xor(v, 8));
      float mn = fmaxf(m_run[j], v);
      alpha[j] = __expf(m_run[j] - mn);
      m_run[j] = mn;
    }
    float p[2][4];
#pragma unroll
    for (int j = 0; j < 4; j++) {
      p[0][j] = __expf(s[0][j] - m_run[j]);
      p[1][j] = __expf(s[1][j] - m_run[j]);
      float sum = p[0][j] + p[1][j];
      sum += __shfl_xor(sum, 1);
      sum += __shfl_xor(sum, 2);
      sum += __shfl_xor(sum, 4);
      sum += __shfl_xor(sum, 8);
      l_run[j] = l_run[j] * alpha[j] + sum;
    }
#pragma unroll
    for (int n = 0; n < 16; n++)
#pragma unroll
      for (int j = 0; j < 4; j++) o_acc[n][j] *= alpha[j];

    // P -> LDS (bf16), then read back as MFMA A-fragment
#pragma unroll
    for (int nf = 0; nf < 2; nf++)
#pragma unroll
      for (int j = 0; j < 4; j++)
        P_lds[w][hi * 4 + j][nf * 16 + lo] = f2bf(p[nf][j]);
    __asm__ volatile("s_waitcnt lgkmcnt(0)" ::: "memory");

    bf16x8 pa = *(const bf16x8*)&P_lds[w][lo][hi * 8];

    // O += P V  (V^T fragments straight from L2-resident Vt)
#pragma unroll
    for (int n = 0; n < 16; n++) {
      bf16x8 vfr = *(const bf16x8*)(vb_base + (size_t)(n * 16 + lo) * SEQ + t * 32 + hi * 8);
      o_acc[n] = __builtin_amdgcn_mfma_f32_16x16x32_bf16(pa, vfr, o_acc[n], 0, 0, 0);
    }
  }

  // epilogue: out = O / l
  {
    int r0 = b * SEQ + qbase + w * 16 + hi * 4;
#pragma unroll
    for (int j = 0; j < 4; j++) {
      float inv = 1.f / l_run[j];
      float* orow = out + (size_t)(r0 + j) * DIM;
#pragma unroll
      for (int n = 0; n < 16; n++)
        orow[n * 16 + lo] = o_acc[n][j] * inv;
    }
  }
}

extern "C" void kernel_launch(void* const* d_in, const int* in_sizes, int n_in,
                              void* d_out, int out_size, void* d_ws, size_t ws_size,
                              hipStream_t stream) {
  const float* x  = (const float*)d_in[0];
  const float* Wq = (const float*)d_in[1];
  const float* Wk = (const float*)d_in[2];
  const float* Wv = (const float*)d_in[3];
  unsigned short* qkv = (unsigned short*)d_ws;
  unsigned short* qb = qkv;                        // 4M elems
  unsigned short* kb = qkv + (size_t)NBATCH * SEQ * DIM;
  unsigned short* vt = kb  + (size_t)NBATCH * SEQ * DIM;
  float* out = (float*)d_out;

  qkv_gemm<<<dim3(128, 4, 3), 256, 0, stream>>>(x, Wq, Wk, Wv, qb, kb, vt);
  attn<<<dim3(SEQ / 32, NBATCH), 128, 0, stream>>>(qb, kb, vt, out);
}

// Round 2
// 515.712 us; speedup vs baseline: 1.3838x; 1.3838x over previous
//
#include <hip/hip_runtime.h>
#include <hip/hip_bf16.h>

// Problem: B=4, S=4096, D=256 single-head causal attention, fp32 in/out.
// ws layout: Qb bf16 [4][4096][256] @ 0, Kb bf16 @ 8MB, Vt bf16 [4][256][4096] @ 16MB (24MB total).

#define SEQ 4096
#define DIM 256
#define NBATCH 4
#define KVBLK 64

typedef __attribute__((ext_vector_type(8))) short bf16x8;
typedef __attribute__((ext_vector_type(4))) float f32x4;
typedef __attribute__((ext_vector_type(4))) unsigned short us4;

static __device__ inline unsigned short f2bf(float f) {
  unsigned int u = __float_as_uint(f);
  u += 0x7FFFu + ((u >> 16) & 1u);   // RNE to bf16
  return (unsigned short)(u >> 16);
}

// ---------------- Kernel 1: QKV projection, C = X @ W^T (bf16 MFMA) -----------------
// grid (M/128, 256/64, 3), block 256 (4 waves). z: 0->Q, 1->K, 2->V (stored transposed).
__global__ __launch_bounds__(256) void qkv_gemm(
    const float* __restrict__ x, const float* __restrict__ Wq,
    const float* __restrict__ Wk, const float* __restrict__ Wv,
    unsigned short* __restrict__ qb, unsigned short* __restrict__ kb,
    unsigned short* __restrict__ vt)
{
  __shared__ unsigned short A_lds[128][40];
  __shared__ unsigned short B_lds[64][40];

  const int tid = threadIdx.x;
  const int lane = tid & 63;
  const int w = tid >> 6;
  const int lo = lane & 15, hi = lane >> 4;
  const int mb = blockIdx.x * 128;
  const int nb = blockIdx.y * 64;
  const int z = blockIdx.z;
  const float* Wm = (z == 0) ? Wq : (z == 1) ? Wk : Wv;

  f32x4 acc[2][4];
#pragma unroll
  for (int mi = 0; mi < 2; mi++)
#pragma unroll
    for (int ni = 0; ni < 4; ni++) acc[mi][ni] = (f32x4){0.f, 0.f, 0.f, 0.f};

  for (int ks = 0; ks < 8; ++ks) {
    const int k0 = ks * 32;
    __syncthreads();
#pragma unroll
    for (int i = 0; i < 4; ++i) {
      int f = tid + i * 256;
      int row = f >> 3, c4 = (f & 7) * 4;
      float4 v = *(const float4*)(x + (size_t)(mb + row) * DIM + k0 + c4);
      us4 bv = { f2bf(v.x), f2bf(v.y), f2bf(v.z), f2bf(v.w) };
      *(us4*)&A_lds[row][c4] = bv;
    }
#pragma unroll
    for (int i = 0; i < 2; ++i) {
      int f = tid + i * 256;
      int row = f >> 3, c4 = (f & 7) * 4;
      float4 v = *(const float4*)(Wm + (size_t)(nb + row) * DIM + k0 + c4);
      us4 bv = { f2bf(v.x), f2bf(v.y), f2bf(v.z), f2bf(v.w) };
      *(us4*)&B_lds[row][c4] = bv;
    }
    __syncthreads();
    bf16x8 a[2], bfr[4];
#pragma unroll
    for (int mi = 0; mi < 2; mi++) a[mi] = *(const bf16x8*)&A_lds[w * 32 + mi * 16 + lo][hi * 8];
#pragma unroll
    for (int ni = 0; ni < 4; ni++) bfr[ni] = *(const bf16x8*)&B_lds[ni * 16 + lo][hi * 8];
#pragma unroll
    for (int mi = 0; mi < 2; mi++)
#pragma unroll
      for (int ni = 0; ni < 4; ni++)
        acc[mi][ni] = __builtin_amdgcn_mfma_f32_16x16x32_bf16(a[mi], bfr[ni], acc[mi][ni], 0, 0, 0);
  }

  if (z < 2) {
    unsigned short* dst = (z == 0) ? qb : kb;
#pragma unroll
    for (int mi = 0; mi < 2; mi++) {
      int r0 = mb + w * 32 + mi * 16 + hi * 4;
#pragma unroll
      for (int ni = 0; ni < 4; ni++) {
        int col = nb + ni * 16 + lo;
#pragma unroll
        for (int j = 0; j < 4; j++)
          dst[(size_t)(r0 + j) * DIM + col] = f2bf(acc[mi][ni][j]);
      }
    }
  } else {
#pragma unroll
    for (int mi = 0; mi < 2; mi++) {
      int s0 = mb + w * 32 + mi * 16 + hi * 4;
      int bidx = s0 >> 12, sl = s0 & 4095;
#pragma unroll
      for (int ni = 0; ni < 4; ni++) {
        int col = nb + ni * 16 + lo;
        us4 pv = { f2bf(acc[mi][ni][0]), f2bf(acc[mi][ni][1]),
                   f2bf(acc[mi][ni][2]), f2bf(acc[mi][ni][3]) };
        *(us4*)(vt + (size_t)bidx * (DIM * SEQ) + (size_t)col * SEQ + sl) = pv;
      }
    }
  }
}

// ---------------- Kernel 2: causal flash attention -----------------
// grid (S/32, B), block 128 (2 waves; wave w owns q rows qbase+16w..+16).
// K tile 64x256 bf16 double-buffered in LDS via global_load_lds (linear dest,
// pre-swizzled source, XOR-swizzled ds_read: byte ^= (row&7)<<4).
__global__ __launch_bounds__(128) void attn(
    const unsigned short* __restrict__ qb, const unsigned short* __restrict__ kb,
    const unsigned short* __restrict__ vt, float* __restrict__ out)
{
  __shared__ unsigned short K_lds[2][KVBLK * DIM];   // 2 x 32KB, swizzled content
  __shared__ unsigned short P_lds[2][16][72];        // per-wave P tile, padded

  const int tid = threadIdx.x;
  const int lane = tid & 63;
  const int w = tid >> 6;
  const int lo = lane & 15, hi = lane >> 4;
  const int qt = blockIdx.x;
  const int b = blockIdx.y;
  const int qbase = qt * 32;
  const int nt = (qt >> 1) + 1;
  const float scale = 0.0625f;  // 1/sqrt(256)

  // Q fragments in registers (16 rows x 256 d per wave)
  bf16x8 qf[8];
  {
    const unsigned short* qrow = qb + (size_t)(b * SEQ + qbase + w * 16 + lo) * DIM;
#pragma unroll
    for (int kk = 0; kk < 8; kk++)
      qf[kk] = *(const bf16x8*)(qrow + kk * 32 + hi * 8);
  }

  float m_run[4], l_run[4];
#pragma unroll
  for (int j = 0; j < 4; j++) { m_run[j] = -__builtin_inff(); l_run[j] = 0.f; }
  f32x4 o_acc[16];
#pragma unroll
  for (int n = 0; n < 16; n++) o_acc[n] = (f32x4){0.f, 0.f, 0.f, 0.f};

  const unsigned short* vb_base = vt + (size_t)b * (DIM * SEQ);
  const char* kb_byte = (const char*)(kb + (size_t)b * SEQ * DIM);
  const int rswz = (lo & 7) << 4;   // read-side XOR (row = nf*16+lo; 16==0 mod 8)

  // prologue: stage tile 0 -> buf 0
  {
    const char* src_base = kb_byte;
#pragma unroll
    for (int i = 0; i < 16; ++i) {
      int L = w * 16384 + i * 1024 + lane * 16;     // linear byte in tile
      int r = L >> 9;                                // row (512B per row)
      int colb = L & 511;
      int srcoff = r * 512 + (colb ^ ((r & 7) << 4));
      __builtin_amdgcn_global_load_lds(
          (const __attribute__((address_space(1))) void*)(src_base + srcoff),
          (__attribute__((address_space(3))) void*)((char*)&K_lds[0][0] + w * 16384 + i * 1024),
          16, 0, 0);
    }
  }
  __syncthreads();

  for (int t = 0; t < nt; ++t) {
    const int cur = t & 1;

    // prefetch next K tile into the other buffer (flies during compute;
    // the compiler's vmcnt(0) drain before the end-of-iter barrier lands cheap)
    if (t + 1 < nt) {
      const char* src_base = kb_byte + (size_t)(t + 1) * KVBLK * DIM * 2;
#pragma unroll
      for (int i = 0; i < 16; ++i) {
        int L = w * 16384 + i * 1024 + lane * 16;
        int r = L >> 9;
        int colb = L & 511;
        int srcoff = r * 512 + (colb ^ ((r & 7) << 4));
        __builtin_amdgcn_global_load_lds(
            (const __attribute__((address_space(1))) void*)(src_base + srcoff),
            (__attribute__((address_space(3))) void*)((char*)&K_lds[cur ^ 1][0] + w * 16384 + i * 1024),
            16, 0, 0);
      }
    }

    // S = Q K^T   (64 kv cols per iter: nf=0..3)
    const char* kt = (const char*)&K_lds[cur][0];
    f32x4 sf[4];
#pragma unroll
    for (int nf = 0; nf < 4; nf++) {
      f32x4 a = (f32x4){0.f, 0.f, 0.f, 0.f};
#pragma unroll
      for (int kk = 0; kk < 8; kk++) {
        int byte_off = (nf * 16 + lo) * 512 + ((kk * 64 + hi * 16) ^ rswz);
        bf16x8 kfr = *(const bf16x8*)(kt + byte_off);
        a = __builtin_amdgcn_mfma_f32_16x16x32_bf16(qf[kk], kfr, a, 0, 0, 0);
      }
      sf[nf] = a;
    }

    // scale + causal mask (only the last tile can touch the diagonal)
    const bool diag = (t == nt - 1);
    float s[4][4];
#pragma unroll
    for (int nf = 0; nf < 4; nf++)
#pragma unroll
      for (int j = 0; j < 4; j++) {
        float v = sf[nf][j] * scale;
        if (diag) {
          int qg = qbase + w * 16 + hi * 4 + j;
          int kg = t * KVBLK + nf * 16 + lo;
          if (kg > qg) v = -__builtin_inff();
        }
        s[nf][j] = v;
      }

    // online softmax (rows in 16-lane groups; j = 4 q-rows per lane)
    float alpha[4];
#pragma unroll
    for (int j = 0; j < 4; j++) {
      float v = fmaxf(fmaxf(s[0][j], s[1][j]), fmaxf(s[2][j], s[3][j]));
      v = fmaxf(v, __shfl_xor(v, 1));
      v = fmaxf(v, __shfl_xor(v, 2));
      v = fmaxf(v, __shfl_xor(v, 4));
      v = fmaxf(v, __shfl_xor(v, 8));
      float mn = fmaxf(m_run[j], v);
      alpha[j] = __expf(m_run[j] - mn);
      m_run[j] = mn;
    }
    float p[4][4];
#pragma unroll
    for (int j = 0; j < 4; j++) {
      float sum = 0.f;
#pragma unroll
      for (int nf = 0; nf < 4; nf++) {
        p[nf][j] = __expf(s[nf][j] - m_run[j]);
        sum += p[nf][j];
      }
      sum += __shfl_xor(sum, 1);
      sum += __shfl_xor(sum, 2);
      sum += __shfl_xor(sum, 4);
      sum += __shfl_xor(sum, 8);
      l_run[j] = l_run[j] * alpha[j] + sum;
    }
#pragma unroll
    for (int n = 0; n < 16; n++)
#pragma unroll
      for (int j = 0; j < 4; j++) o_acc[n][j] *= alpha[j];

    // P -> per-wave LDS (bf16), read back as two A-fragments (k=0..31, 32..63)
#pragma unroll
    for (int nf = 0; nf < 4; nf++)
#pragma unroll
      for (int j = 0; j < 4; j++)
        P_lds[w][hi * 4 + j][nf * 16 + lo] = f2bf(p[nf][j]);

    bf16x8 pa0 = *(const bf16x8*)&P_lds[w][lo][hi * 8];
    bf16x8 pa1 = *(const bf16x8*)&P_lds[w][lo][32 + hi * 8];

    // O += P V  (V^T fragments straight from L2/L3-resident Vt)
    const unsigned short* vtile = vb_base + t * KVBLK + hi * 8;
#pragma unroll
    for (int n = 0; n < 16; n++) {
      const unsigned short* vr = vtile + (size_t)(n * 16 + lo) * SEQ;
      bf16x8 v0 = *(const bf16x8*)(vr);
      bf16x8 v1 = *(const bf16x8*)(vr + 32);
      o_acc[n] = __builtin_amdgcn_mfma_f32_16x16x32_bf16(pa0, v0, o_acc[n], 0, 0, 0);
      o_acc[n] = __builtin_amdgcn_mfma_f32_16x16x32_bf16(pa1, v1, o_acc[n], 0, 0, 0);
    }

    __syncthreads();  // K-buffer handoff (also drains the prefetch)
  }

  // epilogue: out = O / l
  {
    int r0 = b * SEQ + qbase + w * 16 + hi * 4;
#pragma unroll
    for (int j = 0; j < 4; j++) {
      float inv = 1.f / l_run[j];
      float* orow = out + (size_t)(r0 + j) * DIM;
#pragma unroll
      for (int n = 0; n < 16; n++)
        orow[n * 16 + lo] = o_acc[n][j] * inv;
    }
  }
}

extern "C" void kernel_launch(void* const* d_in, const int* in_sizes, int n_in,
                              void* d_out, int out_size, void* d_ws, size_t ws_size,
                              hipStream_t stream) {
  const float* x  = (const float*)d_in[0];
  const float* Wq = (const float*)d_in[1];
  const float* Wk = (const float*)d_in[2];
  const float* Wv = (const float*)d_in[3];
  unsigned short* qkv = (unsigned short*)d_ws;
  unsigned short* qb = qkv;
  unsigned short* kb = qkv + (size_t)NBATCH * SEQ * DIM;
  unsigned short* vt = kb  + (size_t)NBATCH * SEQ * DIM;
  float* out = (float*)d_out;

  qkv_gemm<<<dim3(128, 4, 3), 256, 0, stream>>>(x, Wq, Wk, Wv, qb, kb, vt);
  attn<<<dim3(SEQ / 32, NBATCH), 128, 0, stream>>>(qb, kb, vt, out);
}

// Round 3
// 283.180 us; speedup vs baseline: 2.5201x; 1.8211x over previous
//
#include <hip/hip_runtime.h>
#include <hip/hip_bf16.h>

// Problem: B=4, S=4096, D=256 single-head causal attention, fp32 in/out.
// ws layout: Qb bf16 [4][4096][256] @ 0, Kb bf16 @ 8MB, Vt bf16 [4][256][4096] @ 16MB (24MB total).

#define SEQ 4096
#define DIM 256
#define NBATCH 4
#define KVBLK 64

typedef __attribute__((ext_vector_type(8))) short bf16x8;
typedef __attribute__((ext_vector_type(4))) float f32x4;
typedef __attribute__((ext_vector_type(4))) unsigned short us4;

static __device__ inline unsigned short f2bf(float f) {
  unsigned int u = __float_as_uint(f);
  u += 0x7FFFu + ((u >> 16) & 1u);   // RNE to bf16
  return (unsigned short)(u >> 16);
}

// ---------------- Kernel 1: QKV projection, C = X @ W^T (bf16 MFMA) -----------------
// grid (M/128, 256/64, 3), block 256 (4 waves). z: 0->Q, 1->K, 2->V (stored transposed).
__global__ __launch_bounds__(256) void qkv_gemm(
    const float* __restrict__ x, const float* __restrict__ Wq,
    const float* __restrict__ Wk, const float* __restrict__ Wv,
    unsigned short* __restrict__ qb, unsigned short* __restrict__ kb,
    unsigned short* __restrict__ vt)
{
  __shared__ unsigned short A_lds[128][40];
  __shared__ unsigned short B_lds[64][40];

  const int tid = threadIdx.x;
  const int lane = tid & 63;
  const int w = tid >> 6;
  const int lo = lane & 15, hi = lane >> 4;
  const int mb = blockIdx.x * 128;
  const int nb = blockIdx.y * 64;
  const int z = blockIdx.z;
  const float* Wm = (z == 0) ? Wq : (z == 1) ? Wk : Wv;

  f32x4 acc[2][4];
#pragma unroll
  for (int mi = 0; mi < 2; mi++)
#pragma unroll
    for (int ni = 0; ni < 4; ni++) acc[mi][ni] = (f32x4){0.f, 0.f, 0.f, 0.f};

  for (int ks = 0; ks < 8; ++ks) {
    const int k0 = ks * 32;
    __syncthreads();
#pragma unroll
    for (int i = 0; i < 4; ++i) {
      int f = tid + i * 256;
      int row = f >> 3, c4 = (f & 7) * 4;
      float4 v = *(const float4*)(x + (size_t)(mb + row) * DIM + k0 + c4);
      us4 bv = { f2bf(v.x), f2bf(v.y), f2bf(v.z), f2bf(v.w) };
      *(us4*)&A_lds[row][c4] = bv;
    }
#pragma unroll
    for (int i = 0; i < 2; ++i) {
      int f = tid + i * 256;
      int row = f >> 3, c4 = (f & 7) * 4;
      float4 v = *(const float4*)(Wm + (size_t)(nb + row) * DIM + k0 + c4);
      us4 bv = { f2bf(v.x), f2bf(v.y), f2bf(v.z), f2bf(v.w) };
      *(us4*)&B_lds[row][c4] = bv;
    }
    __syncthreads();
    bf16x8 a[2], bfr[4];
#pragma unroll
    for (int mi = 0; mi < 2; mi++) a[mi] = *(const bf16x8*)&A_lds[w * 32 + mi * 16 + lo][hi * 8];
#pragma unroll
    for (int ni = 0; ni < 4; ni++) bfr[ni] = *(const bf16x8*)&B_lds[ni * 16 + lo][hi * 8];
#pragma unroll
    for (int mi = 0; mi < 2; mi++)
#pragma unroll
      for (int ni = 0; ni < 4; ni++)
        acc[mi][ni] = __builtin_amdgcn_mfma_f32_16x16x32_bf16(a[mi], bfr[ni], acc[mi][ni], 0, 0, 0);
  }

  if (z < 2) {
    unsigned short* dst = (z == 0) ? qb : kb;
#pragma unroll
    for (int mi = 0; mi < 2; mi++) {
      int r0 = mb + w * 32 + mi * 16 + hi * 4;
#pragma unroll
      for (int ni = 0; ni < 4; ni++) {
        int col = nb + ni * 16 + lo;
#pragma unroll
        for (int j = 0; j < 4; j++)
          dst[(size_t)(r0 + j) * DIM + col] = f2bf(acc[mi][ni][j]);
      }
    }
  } else {
#pragma unroll
    for (int mi = 0; mi < 2; mi++) {
      int s0 = mb + w * 32 + mi * 16 + hi * 4;
      int bidx = s0 >> 12, sl = s0 & 4095;
#pragma unroll
      for (int ni = 0; ni < 4; ni++) {
        int col = nb + ni * 16 + lo;
        us4 pv = { f2bf(acc[mi][ni][0]), f2bf(acc[mi][ni][1]),
                   f2bf(acc[mi][ni][2]), f2bf(acc[mi][ni][3]) };
        *(us4*)(vt + (size_t)bidx * (DIM * SEQ) + (size_t)col * SEQ + sl) = pv;
      }
    }
  }
}

// ---------------- Kernel 2: causal flash attention -----------------
// 1-D grid of 256 blocks (1/CU), block 128 (2 waves). Each block processes the
// balanced q-tile pair (127-p, p): exactly 65 KV-tile iterations per block.
// XCD-aware batch mapping: batch = (blockIdx&7)>>1 so each XCD's L2 serves one
// batch (K+V = 4MB). K and V tiles both staged via global_load_lds, double
// buffered, pre-swizzled source + XOR-swizzled ds_read (byte ^= (row&7)<<4).
__global__ __launch_bounds__(128) void attn(
    const unsigned short* __restrict__ qb, const unsigned short* __restrict__ kb,
    const unsigned short* __restrict__ vt, float* __restrict__ out)
{
  __shared__ unsigned short K_lds[2][KVBLK * DIM];   // 2 x 32KB, rows = 512B
  __shared__ unsigned short V_lds[2][KVBLK * DIM];   // 2 x 32KB, [256 d][64 s], rows = 128B
  __shared__ unsigned short P_lds[2][16][72];

  const int tid = threadIdx.x;
  const int lane = tid & 63;
  const int w = tid >> 6;
  const int lo = lane & 15, hi = lane >> 4;
  const int id = blockIdx.x;
  const int xcd = id & 7;
  const int b = xcd >> 1;                       // 0..3, one batch per XCD pair
  const int p = ((id >> 3) << 1) | (xcd & 1);   // 0..63
  const float scale = 0.0625f;  // 1/sqrt(256)

  const char* kb_byte = (const char*)(kb + (size_t)b * SEQ * DIM);
  const char* vt_byte = (const char*)(vt + (size_t)b * SEQ * DIM);
  const int rswz = (lo & 7) << 4;

  // per-wave staging: 16 x 1KB chunks each for K and V (async, no VGPR dest)
  auto stageK = [&](int t, int buf) {
#pragma unroll
    for (int i = 0; i < 16; ++i) {
      int L = (w * 16 + i) * 1024 + lane * 16;   // linear byte in 32KB tile
      int r = L >> 9, colb = L & 511;
      int srcoff = (t * KVBLK + r) * 512 + (colb ^ ((r & 7) << 4));
      __builtin_amdgcn_global_load_lds(
          (const __attribute__((address_space(1))) void*)(kb_byte + srcoff),
          (__attribute__((address_space(3))) void*)((char*)&K_lds[buf][0] + (w * 16 + i) * 1024),
          16, 0, 0);
    }
  };
  auto stageV = [&](int t, int buf) {
#pragma unroll
    for (int i = 0; i < 16; ++i) {
      int L = (w * 16 + i) * 1024 + lane * 16;
      int r = L >> 7, c = L & 127;               // r = d-row 0..255, c = byte in 128B row
      int srcoff = r * (SEQ * 2) + t * (KVBLK * 2) + (c ^ ((r & 7) << 4));
      __builtin_amdgcn_global_load_lds(
          (const __attribute__((address_space(1))) void*)(vt_byte + srcoff),
          (__attribute__((address_space(3))) void*)((char*)&V_lds[buf][0] + (w * 16 + i) * 1024),
          16, 0, 0);
    }
  };

  for (int phase = 0; phase < 2; ++phase) {
    const int qt = phase ? p : 127 - p;
    const int qbase = qt * 32;
    const int nt = (qt >> 1) + 1;

    // Q fragments in registers (16 rows x 256 d per wave)
    bf16x8 qf[8];
    {
      const unsigned short* qrow = qb + (size_t)(b * SEQ + qbase + w * 16 + lo) * DIM;
#pragma unroll
      for (int kk = 0; kk < 8; kk++)
        qf[kk] = *(const bf16x8*)(qrow + kk * 32 + hi * 8);
    }

    float m_run[4], l_run[4];
#pragma unroll
    for (int j = 0; j < 4; j++) { m_run[j] = -__builtin_inff(); l_run[j] = 0.f; }
    f32x4 o_acc[16];
#pragma unroll
    for (int n = 0; n < 16; n++) o_acc[n] = (f32x4){0.f, 0.f, 0.f, 0.f};

    stageK(0, 0);
    stageV(0, 0);
    __syncthreads();

    for (int t = 0; t < nt; ++t) {
      const int cur = t & 1;
      if (t + 1 < nt) { stageK(t + 1, cur ^ 1); stageV(t + 1, cur ^ 1); }

      // S = Q K^T   (64 kv cols: nf=0..3)
      const char* kt = (const char*)&K_lds[cur][0];
      f32x4 sf[4];
#pragma unroll
      for (int nf = 0; nf < 4; nf++) {
        f32x4 a = (f32x4){0.f, 0.f, 0.f, 0.f};
#pragma unroll
        for (int kk = 0; kk < 8; kk++) {
          int byte_off = (nf * 16 + lo) * 512 + ((kk * 64 + hi * 16) ^ rswz);
          bf16x8 kfr = *(const bf16x8*)(kt + byte_off);
          a = __builtin_amdgcn_mfma_f32_16x16x32_bf16(qf[kk], kfr, a, 0, 0, 0);
        }
        sf[nf] = a;
      }

      // scale + causal mask (only the last tile can touch the diagonal)
      const bool diag = (t == nt - 1);
      float s[4][4];
#pragma unroll
      for (int nf = 0; nf < 4; nf++)
#pragma unroll
        for (int j = 0; j < 4; j++) {
          float v = sf[nf][j] * scale;
          if (diag) {
            int qg = qbase + w * 16 + hi * 4 + j;
            int kg = t * KVBLK + nf * 16 + lo;
            if (kg > qg) v = -__builtin_inff();
          }
          s[nf][j] = v;
        }

      // online softmax (rows in 16-lane groups; j = 4 q-rows per lane)
      float alpha[4];
#pragma unroll
      for (int j = 0; j < 4; j++) {
        float v = fmaxf(fmaxf(s[0][j], s[1][j]), fmaxf(s[2][j], s[3][j]));
        v = fmaxf(v, __shfl_xor(v, 1));
        v = fmaxf(v, __shfl_xor(v, 2));
        v = fmaxf(v, __shfl_xor(v, 4));
        v = fmaxf(v, __shfl_xor(v, 8));
        float mn = fmaxf(m_run[j], v);
        alpha[j] = __expf(m_run[j] - mn);
        m_run[j] = mn;
      }
      float pr[4][4];
#pragma unroll
      for (int j = 0; j < 4; j++) {
        float sum = 0.f;
#pragma unroll
        for (int nf = 0; nf < 4; nf++) {
          pr[nf][j] = __expf(s[nf][j] - m_run[j]);
          sum += pr[nf][j];
        }
        sum += __shfl_xor(sum, 1);
        sum += __shfl_xor(sum, 2);
        sum += __shfl_xor(sum, 4);
        sum += __shfl_xor(sum, 8);
        l_run[j] = l_run[j] * alpha[j] + sum;
      }
#pragma unroll
      for (int n = 0; n < 16; n++)
#pragma unroll
        for (int j = 0; j < 4; j++) o_acc[n][j] *= alpha[j];

      // P -> per-wave LDS (bf16), read back as two A-fragments (k=0..31, 32..63)
#pragma unroll
      for (int nf = 0; nf < 4; nf++)
#pragma unroll
        for (int j = 0; j < 4; j++)
          P_lds[w][hi * 4 + j][nf * 16 + lo] = f2bf(pr[nf][j]);

      bf16x8 pa0 = *(const bf16x8*)&P_lds[w][lo][hi * 8];
      bf16x8 pa1 = *(const bf16x8*)&P_lds[w][lo][32 + hi * 8];

      // O += P V  (V from swizzled LDS tile [256][64])
      const char* vtl = (const char*)&V_lds[cur][0];
#pragma unroll
      for (int n = 0; n < 16; n++) {
        int rowb = (n * 16 + lo) * 128;
        bf16x8 v0 = *(const bf16x8*)(vtl + rowb + ((hi * 16) ^ rswz));
        bf16x8 v1 = *(const bf16x8*)(vtl + rowb + ((64 + hi * 16) ^ rswz));
        o_acc[n] = __builtin_amdgcn_mfma_f32_16x16x32_bf16(pa0, v0, o_acc[n], 0, 0, 0);
        o_acc[n] = __builtin_amdgcn_mfma_f32_16x16x32_bf16(pa1, v1, o_acc[n], 0, 0, 0);
      }

      __syncthreads();  // buffer handoff (drains prefetch vmcnt)
    }

    // epilogue: out = O / l
    {
      int r0 = b * SEQ + qbase + w * 16 + hi * 4;
#pragma unroll
      for (int j = 0; j < 4; j++) {
        float inv = 1.f / l_run[j];
        float* orow = out + (size_t)(r0 + j) * DIM;
#pragma unroll
        for (int n = 0; n < 16; n++)
          orow[n * 16 + lo] = o_acc[n][j] * inv;
      }
    }
  }
}

extern "C" void kernel_launch(void* const* d_in, const int* in_sizes, int n_in,
                              void* d_out, int out_size, void* d_ws, size_t ws_size,
                              hipStream_t stream) {
  const float* x  = (const float*)d_in[0];
  const float* Wq = (const float*)d_in[1];
  const float* Wk = (const float*)d_in[2];
  const float* Wv = (const float*)d_in[3];
  unsigned short* qkv = (unsigned short*)d_ws;
  unsigned short* qb = qkv;
  unsigned short* kb = qkv + (size_t)NBATCH * SEQ * DIM;
  unsigned short* vt = kb  + (size_t)NBATCH * SEQ * DIM;
  float* out = (float*)d_out;

  qkv_gemm<<<dim3(128, 4, 3), 256, 0, stream>>>(x, Wq, Wk, Wv, qb, kb, vt);
  attn<<<dim3(256), 128, 0, stream>>>(qb, kb, vt, out);
}

// Round 4
// 257.754 us; speedup vs baseline: 2.7687x; 1.0986x over previous
//
#include <hip/hip_runtime.h>
#include <hip/hip_bf16.h>

// Problem: B=4, S=4096, D=256 single-head causal attention, fp32 in/out.
// ws layout: Qb bf16 [4][4096][256] @ 0 (8MB);
//            KV @ 8MB: per (batch, kv-tile t<64) a contiguous 64KB block:
//              bytes 0..32767  : K tile, swizzled image of [64 s][512B row]:
//                                byte (r*512 + 2*d) ^ ((r&7)<<4)
//              bytes 32768..   : V tile, swizzled image of [256 d][128B row]:
//                                byte (d*128 + 2*s) ^ ((d&7)<<4)
// Staging in attn is then a pure linear 64KB stream via global_load_lds.

#define SEQ 4096
#define DIM 256
#define NBATCH 4
#define KVBLK 64
#define KVT_BYTES 65536

typedef __attribute__((ext_vector_type(8))) short bf16x8;
typedef __attribute__((ext_vector_type(4))) float f32x4;
typedef __attribute__((ext_vector_type(4))) unsigned short us4;

static __device__ inline unsigned short f2bf(float f) {
  unsigned int u = __float_as_uint(f);
  u += 0x7FFFu + ((u >> 16) & 1u);   // RNE to bf16
  return (unsigned short)(u >> 16);
}

// ---------------- Kernel 1: QKV projection, C = X @ W^T (bf16 MFMA) -----------------
// grid (M/128, 256/64, 3), block 256 (4 waves). z: 0->Q, 1->K, 2->V.
__global__ __launch_bounds__(256) void qkv_gemm(
    const float* __restrict__ x, const float* __restrict__ Wq,
    const float* __restrict__ Wk, const float* __restrict__ Wv,
    unsigned short* __restrict__ qb, char* __restrict__ kv)
{
  __shared__ unsigned short A_lds[128][40];
  __shared__ unsigned short B_lds[64][40];

  const int tid = threadIdx.x;
  const int lane = tid & 63;
  const int w = tid >> 6;
  const int lo = lane & 15, hi = lane >> 4;
  const int mb = blockIdx.x * 128;
  const int nb = blockIdx.y * 64;
  const int z = blockIdx.z;
  const float* Wm = (z == 0) ? Wq : (z == 1) ? Wk : Wv;

  f32x4 acc[2][4];
#pragma unroll
  for (int mi = 0; mi < 2; mi++)
#pragma unroll
    for (int ni = 0; ni < 4; ni++) acc[mi][ni] = (f32x4){0.f, 0.f, 0.f, 0.f};

  for (int ks = 0; ks < 8; ++ks) {
    const int k0 = ks * 32;
    __syncthreads();
#pragma unroll
    for (int i = 0; i < 4; ++i) {
      int f = tid + i * 256;
      int row = f >> 3, c4 = (f & 7) * 4;
      float4 v = *(const float4*)(x + (size_t)(mb + row) * DIM + k0 + c4);
      us4 bv = { f2bf(v.x), f2bf(v.y), f2bf(v.z), f2bf(v.w) };
      *(us4*)&A_lds[row][c4] = bv;
    }
#pragma unroll
    for (int i = 0; i < 2; ++i) {
      int f = tid + i * 256;
      int row = f >> 3, c4 = (f & 7) * 4;
      float4 v = *(const float4*)(Wm + (size_t)(nb + row) * DIM + k0 + c4);
      us4 bv = { f2bf(v.x), f2bf(v.y), f2bf(v.z), f2bf(v.w) };
      *(us4*)&B_lds[row][c4] = bv;
    }
    __syncthreads();
    bf16x8 a[2], bfr[4];
#pragma unroll
    for (int mi = 0; mi < 2; mi++) a[mi] = *(const bf16x8*)&A_lds[w * 32 + mi * 16 + lo][hi * 8];
#pragma unroll
    for (int ni = 0; ni < 4; ni++) bfr[ni] = *(const bf16x8*)&B_lds[ni * 16 + lo][hi * 8];
#pragma unroll
    for (int mi = 0; mi < 2; mi++)
#pragma unroll
      for (int ni = 0; ni < 4; ni++)
        acc[mi][ni] = __builtin_amdgcn_mfma_f32_16x16x32_bf16(a[mi], bfr[ni], acc[mi][ni], 0, 0, 0);
  }

  if (z == 0) {
#pragma unroll
    for (int mi = 0; mi < 2; mi++) {
      int r0 = mb + w * 32 + mi * 16 + hi * 4;
#pragma unroll
      for (int ni = 0; ni < 4; ni++) {
        int col = nb + ni * 16 + lo;
#pragma unroll
        for (int j = 0; j < 4; j++)
          qb[(size_t)(r0 + j) * DIM + col] = f2bf(acc[mi][ni][j]);
      }
    }
  } else if (z == 1) {
    // K: swizzled tile image, scalar 2B stores
#pragma unroll
    for (int mi = 0; mi < 2; mi++) {
      int r0 = mb + w * 32 + mi * 16 + hi * 4;
#pragma unroll
      for (int ni = 0; ni < 4; ni++) {
        int d = nb + ni * 16 + lo;
#pragma unroll
        for (int j = 0; j < 4; j++) {
          int srow = r0 + j;
          int bb = srow >> 12, sl = srow & 4095;
          int t = sl >> 6, r = sl & 63;
          size_t byte = ((size_t)(bb * 64 + t)) * KVT_BYTES +
                        (size_t)((r * 512 + 2 * d) ^ ((r & 7) << 4));
          *(unsigned short*)(kv + byte) = f2bf(acc[mi][ni][j]);
        }
      }
    }
  } else {
    // V: swizzled tile image, 8B stores (4 consecutive s per lane)
#pragma unroll
    for (int mi = 0; mi < 2; mi++) {
      int s0 = mb + w * 32 + mi * 16 + hi * 4;
      int bb = s0 >> 12, sl = s0 & 4095;
      int t = sl >> 6, sI = sl & 63;
#pragma unroll
      for (int ni = 0; ni < 4; ni++) {
        int d = nb + ni * 16 + lo;
        us4 pv = { f2bf(acc[mi][ni][0]), f2bf(acc[mi][ni][1]),
                   f2bf(acc[mi][ni][2]), f2bf(acc[mi][ni][3]) };
        size_t byte = ((size_t)(bb * 64 + t)) * KVT_BYTES + 32768 +
                      (size_t)((d * 128 + 2 * sI) ^ ((d & 7) << 4));
        *(us4*)(kv + byte) = pv;
      }
    }
  }
}

// ---------------- Kernel 2: causal flash attention -----------------
// 256 blocks (1/CU), 128 thr (2 waves). Block handles the balanced q-tile pair
// (127-p, p): 65 KV-tile iterations. batch = (blockIdx&7)>>1 (XCD-local K/V).
// K+V tile = one linear 64KB stream via global_load_lds, double-buffered;
// ds_read side applies the XOR swizzle baked into the global image.
__global__ __launch_bounds__(128) void attn(
    const unsigned short* __restrict__ qb, const char* __restrict__ kv,
    float* __restrict__ out)
{
  __shared__ char KV_lds[2][KVT_BYTES];       // [K 32KB | V 32KB] per buffer
  __shared__ unsigned short P_lds[2][16][72];

  const int tid = threadIdx.x;
  const int lane = tid & 63;
  const int w = tid >> 6;
  const int lo = lane & 15, hi = lane >> 4;
  const int id = blockIdx.x;
  const int xcd = id & 7;
  const int b = xcd >> 1;
  const int p = ((id >> 3) << 1) | (xcd & 1);   // 0..63
  const float scale = 0.0625f;  // 1/sqrt(256)

  const char* kv_base = kv + (size_t)b * 64 * KVT_BYTES;
  const int rswz = (lo & 7) << 4;

  auto stageKV = [&](int t, int buf) {
    const char* src = kv_base + (size_t)t * KVT_BYTES + w * 32768 + lane * 16;
    char* dst = &KV_lds[buf][0] + w * 32768 + lane * 16;
#pragma unroll
    for (int i = 0; i < 32; ++i) {
      __builtin_amdgcn_global_load_lds(
          (const __attribute__((address_space(1))) void*)(src + i * 1024),
          (__attribute__((address_space(3))) void*)(dst + i * 1024),
          16, 0, 0);
    }
  };

  for (int phase = 0; phase < 2; ++phase) {
    const int qt = phase ? p : 127 - p;
    const int qbase = qt * 32;
    const int nt = (qt >> 1) + 1;

    bf16x8 qf[8];
    {
      const unsigned short* qrow = qb + (size_t)(b * SEQ + qbase + w * 16 + lo) * DIM;
#pragma unroll
      for (int kk = 0; kk < 8; kk++)
        qf[kk] = *(const bf16x8*)(qrow + kk * 32 + hi * 8);
    }

    float m_run[4], l_run[4];
#pragma unroll
    for (int j = 0; j < 4; j++) { m_run[j] = -__builtin_inff(); l_run[j] = 0.f; }
    f32x4 o_acc[16];
#pragma unroll
    for (int n = 0; n < 16; n++) o_acc[n] = (f32x4){0.f, 0.f, 0.f, 0.f};

    stageKV(0, 0);
    __syncthreads();

    for (int t = 0; t < nt; ++t) {
      const int cur = t & 1;
      if (t + 1 < nt) stageKV(t + 1, cur ^ 1);

      // S = Q K^T   (64 kv cols: nf=0..3)
      const char* kt = &KV_lds[cur][0];
      f32x4 sf[4];
#pragma unroll
      for (int nf = 0; nf < 4; nf++) {
        f32x4 a = (f32x4){0.f, 0.f, 0.f, 0.f};
#pragma unroll
        for (int kk = 0; kk < 8; kk++) {
          int byte_off = (nf * 16 + lo) * 512 + ((kk * 64 + hi * 16) ^ rswz);
          bf16x8 kfr = *(const bf16x8*)(kt + byte_off);
          a = __builtin_amdgcn_mfma_f32_16x16x32_bf16(qf[kk], kfr, a, 0, 0, 0);
        }
        sf[nf] = a;
      }

      // scale + causal mask (only the last tile can touch the diagonal)
      const bool diag = (t == nt - 1);
      float s[4][4];
#pragma unroll
      for (int nf = 0; nf < 4; nf++)
#pragma unroll
        for (int j = 0; j < 4; j++) {
          float v = sf[nf][j] * scale;
          if (diag) {
            int qg = qbase + w * 16 + hi * 4 + j;
            int kg = t * KVBLK + nf * 16 + lo;
            if (kg > qg) v = -__builtin_inff();
          }
          s[nf][j] = v;
        }

      // online softmax with defer-max (T13): skip rescale unless max grew > 8
      float vnew[4];
#pragma unroll
      for (int j = 0; j < 4; j++) {
        float v = fmaxf(fmaxf(s[0][j], s[1][j]), fmaxf(s[2][j], s[3][j]));
        v = fmaxf(v, __shfl_xor(v, 1));
        v = fmaxf(v, __shfl_xor(v, 2));
        v = fmaxf(v, __shfl_xor(v, 4));
        v = fmaxf(v, __shfl_xor(v, 8));
        vnew[j] = v;
      }
      bool grow = false;
#pragma unroll
      for (int j = 0; j < 4; j++) grow = grow || (vnew[j] > m_run[j] + 8.f);
      if (__any(grow)) {
#pragma unroll
        for (int j = 0; j < 4; j++) {
          float mn = fmaxf(m_run[j], vnew[j]);
          float alpha = __expf(m_run[j] - mn);
          m_run[j] = mn;
          l_run[j] *= alpha;
#pragma unroll
          for (int n = 0; n < 16; n++) o_acc[n][j] *= alpha;
        }
      }
      float pr[4][4];
#pragma unroll
      for (int j = 0; j < 4; j++) {
        float sum = 0.f;
#pragma unroll
        for (int nf = 0; nf < 4; nf++) {
          pr[nf][j] = __expf(s[nf][j] - m_run[j]);
          sum += pr[nf][j];
        }
        sum += __shfl_xor(sum, 1);
        sum += __shfl_xor(sum, 2);
        sum += __shfl_xor(sum, 4);
        sum += __shfl_xor(sum, 8);
        l_run[j] += sum;
      }

      // P -> per-wave LDS (bf16), read back as two A-fragments (k=0..31, 32..63)
#pragma unroll
      for (int nf = 0; nf < 4; nf++)
#pragma unroll
        for (int j = 0; j < 4; j++)
          P_lds[w][hi * 4 + j][nf * 16 + lo] = f2bf(pr[nf][j]);

      bf16x8 pa0 = *(const bf16x8*)&P_lds[w][lo][hi * 8];
      bf16x8 pa1 = *(const bf16x8*)&P_lds[w][lo][32 + hi * 8];

      // O += P V  (V from swizzled LDS half-tile [256 d][128B])
      const char* vtl = &KV_lds[cur][32768];
#pragma unroll
      for (int n = 0; n < 16; n++) {
        int rowb = (n * 16 + lo) * 128;
        bf16x8 v0 = *(const bf16x8*)(vtl + rowb + ((hi * 16) ^ rswz));
        bf16x8 v1 = *(const bf16x8*)(vtl + rowb + ((64 + hi * 16) ^ rswz));
        o_acc[n] = __builtin_amdgcn_mfma_f32_16x16x32_bf16(pa0, v0, o_acc[n], 0, 0, 0);
        o_acc[n] = __builtin_amdgcn_mfma_f32_16x16x32_bf16(pa1, v1, o_acc[n], 0, 0, 0);
      }

      __syncthreads();  // buffer handoff (drains prefetch vmcnt)
    }

    // epilogue: out = O / l
    {
      int r0 = b * SEQ + qbase + w * 16 + hi * 4;
#pragma unroll
      for (int j = 0; j < 4; j++) {
        float inv = 1.f / l_run[j];
        float* orow = out + (size_t)(r0 + j) * DIM;
#pragma unroll
        for (int n = 0; n < 16; n++)
          orow[n * 16 + lo] = o_acc[n][j] * inv;
      }
    }
  }
}

extern "C" void kernel_launch(void* const* d_in, const int* in_sizes, int n_in,
                              void* d_out, int out_size, void* d_ws, size_t ws_size,
                              hipStream_t stream) {
  const float* x  = (const float*)d_in[0];
  const float* Wq = (const float*)d_in[1];
  const float* Wk = (const float*)d_in[2];
  const float* Wv = (const float*)d_in[3];
  unsigned short* qb = (unsigned short*)d_ws;                       // 8MB
  char* kv = (char*)d_ws + (size_t)NBATCH * SEQ * DIM * 2;          // 16MB
  float* out = (float*)d_out;

  qkv_gemm<<<dim3(128, 4, 3), 256, 0, stream>>>(x, Wq, Wk, Wv, qb, kv);
  attn<<<dim3(256), 128, 0, stream>>>(qb, kv, out);
}

// Round 5
// 254.530 us; speedup vs baseline: 2.8038x; 1.0127x over previous
//
#include <hip/hip_runtime.h>
#include <hip/hip_bf16.h>

// Problem: B=4, S=4096, D=256 single-head causal attention, fp32 in/out.
// ws layout: Qb bf16 [4][4096][256] @ 0 (8MB);
//            KV @ 8MB: per (batch, kv-tile t<64) a contiguous 64KB block:
//              bytes 0..32767  : K tile, swizzled image of [64 s][512B row]:
//                                byte (r*512 + 2*d) ^ ((r&7)<<4)
//              bytes 32768..   : V tile, swizzled image of [256 d][128B row]:
//                                byte (d*128 + 2*s) ^ ((d&7)<<4)
// attn staging = pure linear 64KB stream via global_load_lds, counted-vmcnt
// pipelined (T3+T4): stage t+2 issued at end of iter t, waited 1 iter later.

#define SEQ 4096
#define DIM 256
#define NBATCH 4
#define KVBLK 64
#define KVT_BYTES 65536

typedef __attribute__((ext_vector_type(8))) short bf16x8;
typedef __attribute__((ext_vector_type(4))) float f32x4;
typedef __attribute__((ext_vector_type(4))) unsigned short us4;

static __device__ inline unsigned short f2bf(float f) {
  unsigned int u = __float_as_uint(f);
  u += 0x7FFFu + ((u >> 16) & 1u);   // RNE to bf16
  return (unsigned short)(u >> 16);
}

// ---------------- Kernel 1: QKV projection, C = X @ W^T (bf16 MFMA) -----------------
// grid (M/128, 256/64, 3), block 256 (4 waves). z: 0->Q, 1->K, 2->V.
__global__ __launch_bounds__(256) void qkv_gemm(
    const float* __restrict__ x, const float* __restrict__ Wq,
    const float* __restrict__ Wk, const float* __restrict__ Wv,
    unsigned short* __restrict__ qb, char* __restrict__ kv)
{
  __shared__ unsigned short A_lds[128][40];
  __shared__ unsigned short B_lds[64][40];

  const int tid = threadIdx.x;
  const int lane = tid & 63;
  const int w = tid >> 6;
  const int lo = lane & 15, hi = lane >> 4;
  const int mb = blockIdx.x * 128;
  const int nb = blockIdx.y * 64;
  const int z = blockIdx.z;
  const float* Wm = (z == 0) ? Wq : (z == 1) ? Wk : Wv;

  f32x4 acc[2][4];
#pragma unroll
  for (int mi = 0; mi < 2; mi++)
#pragma unroll
    for (int ni = 0; ni < 4; ni++) acc[mi][ni] = (f32x4){0.f, 0.f, 0.f, 0.f};

  for (int ks = 0; ks < 8; ++ks) {
    const int k0 = ks * 32;
    __syncthreads();
#pragma unroll
    for (int i = 0; i < 4; ++i) {
      int f = tid + i * 256;
      int row = f >> 3, c4 = (f & 7) * 4;
      float4 v = *(const float4*)(x + (size_t)(mb + row) * DIM + k0 + c4);
      us4 bv = { f2bf(v.x), f2bf(v.y), f2bf(v.z), f2bf(v.w) };
      *(us4*)&A_lds[row][c4] = bv;
    }
#pragma unroll
    for (int i = 0; i < 2; ++i) {
      int f = tid + i * 256;
      int row = f >> 3, c4 = (f & 7) * 4;
      float4 v = *(const float4*)(Wm + (size_t)(nb + row) * DIM + k0 + c4);
      us4 bv = { f2bf(v.x), f2bf(v.y), f2bf(v.z), f2bf(v.w) };
      *(us4*)&B_lds[row][c4] = bv;
    }
    __syncthreads();
    bf16x8 a[2], bfr[4];
#pragma unroll
    for (int mi = 0; mi < 2; mi++) a[mi] = *(const bf16x8*)&A_lds[w * 32 + mi * 16 + lo][hi * 8];
#pragma unroll
    for (int ni = 0; ni < 4; ni++) bfr[ni] = *(const bf16x8*)&B_lds[ni * 16 + lo][hi * 8];
#pragma unroll
    for (int mi = 0; mi < 2; mi++)
#pragma unroll
      for (int ni = 0; ni < 4; ni++)
        acc[mi][ni] = __builtin_amdgcn_mfma_f32_16x16x32_bf16(a[mi], bfr[ni], acc[mi][ni], 0, 0, 0);
  }

  if (z == 0) {
#pragma unroll
    for (int mi = 0; mi < 2; mi++) {
      int r0 = mb + w * 32 + mi * 16 + hi * 4;
#pragma unroll
      for (int ni = 0; ni < 4; ni++) {
        int col = nb + ni * 16 + lo;
#pragma unroll
        for (int j = 0; j < 4; j++)
          qb[(size_t)(r0 + j) * DIM + col] = f2bf(acc[mi][ni][j]);
      }
    }
  } else if (z == 1) {
    // K: swizzled tile image, scalar 2B stores
#pragma unroll
    for (int mi = 0; mi < 2; mi++) {
      int r0 = mb + w * 32 + mi * 16 + hi * 4;
#pragma unroll
      for (int ni = 0; ni < 4; ni++) {
        int d = nb + ni * 16 + lo;
#pragma unroll
        for (int j = 0; j < 4; j++) {
          int srow = r0 + j;
          int bb = srow >> 12, sl = srow & 4095;
          int t = sl >> 6, r = sl & 63;
          size_t byte = ((size_t)(bb * 64 + t)) * KVT_BYTES +
                        (size_t)((r * 512 + 2 * d) ^ ((r & 7) << 4));
          *(unsigned short*)(kv + byte) = f2bf(acc[mi][ni][j]);
        }
      }
    }
  } else {
    // V: swizzled tile image, 8B stores (4 consecutive s per lane)
#pragma unroll
    for (int mi = 0; mi < 2; mi++) {
      int s0 = mb + w * 32 + mi * 16 + hi * 4;
      int bb = s0 >> 12, sl = s0 & 4095;
      int t = sl >> 6, sI = sl & 63;
#pragma unroll
      for (int ni = 0; ni < 4; ni++) {
        int d = nb + ni * 16 + lo;
        us4 pv = { f2bf(acc[mi][ni][0]), f2bf(acc[mi][ni][1]),
                   f2bf(acc[mi][ni][2]), f2bf(acc[mi][ni][3]) };
        size_t byte = ((size_t)(bb * 64 + t)) * KVT_BYTES + 32768 +
                      (size_t)((d * 128 + 2 * sI) ^ ((d & 7) << 4));
        *(us4*)(kv + byte) = pv;
      }
    }
  }
}

// ---------------- Kernel 2: causal flash attention -----------------
// 256 blocks (1/CU), 128 thr (2 waves). Block handles the balanced q-tile pair
// (127-p, p): 65 KV-tile iterations. batch = (blockIdx&7)>>1 (XCD-local K/V).
// Counted-vmcnt double-buffer pipeline: per iter {wait vmcnt(32); barrier;
// compute; barrier; stage t+2}. vmcnt(0) only at last iter / phase boundary.
__global__ __launch_bounds__(128) void attn(
    const unsigned short* __restrict__ qb, const char* __restrict__ kv,
    float* __restrict__ out)
{
  __shared__ char KV_lds[2][KVT_BYTES];       // [K 32KB | V 32KB] per buffer
  __shared__ unsigned short P_lds[2][16][72];

  const int tid = threadIdx.x;
  const int lane = tid & 63;
  const int w = tid >> 6;
  const int lo = lane & 15, hi = lane >> 4;
  const int id = blockIdx.x;
  const int xcd = id & 7;
  const int b = xcd >> 1;
  const int p = ((id >> 3) << 1) | (xcd & 1);   // 0..63
  const float scale = 0.0625f;  // 1/sqrt(256)

  const char* kv_base = kv + (size_t)b * 64 * KVT_BYTES;
  const int rswz = (lo & 7) << 4;

  auto stageKV = [&](int t, int buf) {
    const char* src = kv_base + (size_t)t * KVT_BYTES + w * 32768 + lane * 16;
    char* dst = &KV_lds[buf][0] + w * 32768 + lane * 16;
#pragma unroll
    for (int i = 0; i < 32; ++i) {
      __builtin_amdgcn_global_load_lds(
          (const __attribute__((address_space(1))) void*)(src + i * 1024),
          (__attribute__((address_space(3))) void*)(dst + i * 1024),
          16, 0, 0);
    }
  };

  for (int phase = 0; phase < 2; ++phase) {
    const int qt = phase ? p : 127 - p;
    const int qbase = qt * 32;
    const int nt = (qt >> 1) + 1;

    // Q fragments first (their vmcnt retires at the phase-entry drain)
    bf16x8 qf[8];
    {
      const unsigned short* qrow = qb + (size_t)(b * SEQ + qbase + w * 16 + lo) * DIM;
#pragma unroll
      for (int kk = 0; kk < 8; kk++)
        qf[kk] = *(const bf16x8*)(qrow + kk * 32 + hi * 8);
    }

    // phase-entry drain: previous phase's stages/stores fully retired,
    // then prime the pipeline (tiles 0 and 1).
    asm volatile("s_waitcnt vmcnt(0)" ::: "memory");
    __builtin_amdgcn_sched_barrier(0);
    __builtin_amdgcn_s_barrier();
    stageKV(0, 0);
    if (nt > 1) stageKV(1, 1);

    float m_run[4], l_run[4];
#pragma unroll
    for (int j = 0; j < 4; j++) { m_run[j] = -__builtin_inff(); l_run[j] = 0.f; }
    f32x4 o_acc[16];
#pragma unroll
    for (int n = 0; n < 16; n++) o_acc[n] = (f32x4){0.f, 0.f, 0.f, 0.f};

    for (int t = 0; t < nt; ++t) {
      const int cur = t & 1;

      // wait: stage(t) complete; stage(t+1) (32 loads) may stay in flight
      if (t + 1 < nt) {
        asm volatile("s_waitcnt vmcnt(32)" ::: "memory");
      } else {
        asm volatile("s_waitcnt vmcnt(0)" ::: "memory");
      }
      __builtin_amdgcn_sched_barrier(0);
      __builtin_amdgcn_s_barrier();   // all waves: buffer cur is ready

      // S = Q K^T   (64 kv cols: nf=0..3)
      const char* kt = &KV_lds[cur][0];
      f32x4 sf[4];
#pragma unroll
      for (int nf = 0; nf < 4; nf++) {
        f32x4 a = (f32x4){0.f, 0.f, 0.f, 0.f};
#pragma unroll
        for (int kk = 0; kk < 8; kk++) {
          int byte_off = (nf * 16 + lo) * 512 + ((kk * 64 + hi * 16) ^ rswz);
          bf16x8 kfr = *(const bf16x8*)(kt + byte_off);
          a = __builtin_amdgcn_mfma_f32_16x16x32_bf16(qf[kk], kfr, a, 0, 0, 0);
        }
        sf[nf] = a;
      }

      // scale + causal mask (only the last tile can touch the diagonal)
      const bool diag = (t == nt - 1);
      float s[4][4];
#pragma unroll
      for (int nf = 0; nf < 4; nf++)
#pragma unroll
        for (int j = 0; j < 4; j++) {
          float v = sf[nf][j] * scale;
          if (diag) {
            int qg = qbase + w * 16 + hi * 4 + j;
            int kg = t * KVBLK + nf * 16 + lo;
            if (kg > qg) v = -__builtin_inff();
          }
          s[nf][j] = v;
        }

      // online softmax with defer-max (T13): skip rescale unless max grew > 8
      float vnew[4];
#pragma unroll
      for (int j = 0; j < 4; j++) {
        float v = fmaxf(fmaxf(s[0][j], s[1][j]), fmaxf(s[2][j], s[3][j]));
        v = fmaxf(v, __shfl_xor(v, 1));
        v = fmaxf(v, __shfl_xor(v, 2));
        v = fmaxf(v, __shfl_xor(v, 4));
        v = fmaxf(v, __shfl_xor(v, 8));
        vnew[j] = v;
      }
      bool grow = false;
#pragma unroll
      for (int j = 0; j < 4; j++) grow = grow || (vnew[j] > m_run[j] + 8.f);
      if (__any(grow)) {
#pragma unroll
        for (int j = 0; j < 4; j++) {
          float mn = fmaxf(m_run[j], vnew[j]);
          float alpha = __expf(m_run[j] - mn);
          m_run[j] = mn;
          l_run[j] *= alpha;
#pragma unroll
          for (int n = 0; n < 16; n++) o_acc[n][j] *= alpha;
        }
      }
      float pr[4][4];
#pragma unroll
      for (int j = 0; j < 4; j++) {
        float sum = 0.f;
#pragma unroll
        for (int nf = 0; nf < 4; nf++) {
          pr[nf][j] = __expf(s[nf][j] - m_run[j]);
          sum += pr[nf][j];
        }
        sum += __shfl_xor(sum, 1);
        sum += __shfl_xor(sum, 2);
        sum += __shfl_xor(sum, 4);
        sum += __shfl_xor(sum, 8);
        l_run[j] += sum;
      }

      // P -> per-wave LDS (bf16), read back as two A-fragments (k=0..31, 32..63)
#pragma unroll
      for (int nf = 0; nf < 4; nf++)
#pragma unroll
        for (int j = 0; j < 4; j++)
          P_lds[w][hi * 4 + j][nf * 16 + lo] = f2bf(pr[nf][j]);

      bf16x8 pa0 = *(const bf16x8*)&P_lds[w][lo][hi * 8];
      bf16x8 pa1 = *(const bf16x8*)&P_lds[w][lo][32 + hi * 8];

      // O += P V  (V from swizzled LDS half-tile [256 d][128B])
      const char* vtl = &KV_lds[cur][32768];
#pragma unroll
      for (int n = 0; n < 16; n++) {
        int rowb = (n * 16 + lo) * 128;
        bf16x8 v0 = *(const bf16x8*)(vtl + rowb + ((hi * 16) ^ rswz));
        bf16x8 v1 = *(const bf16x8*)(vtl + rowb + ((64 + hi * 16) ^ rswz));
        o_acc[n] = __builtin_amdgcn_mfma_f32_16x16x32_bf16(pa0, v0, o_acc[n], 0, 0, 0);
        o_acc[n] = __builtin_amdgcn_mfma_f32_16x16x32_bf16(pa1, v1, o_acc[n], 0, 0, 0);
      }

      __builtin_amdgcn_sched_barrier(0);
      __builtin_amdgcn_s_barrier();   // all waves done reading cur
      if (t + 2 < nt) stageKV(t + 2, cur);   // overwrite freed buffer; waited at iter t+2
    }

    // epilogue: out = O / l
    {
      int r0 = b * SEQ + qbase + w * 16 + hi * 4;
#pragma unroll
      for (int j = 0; j < 4; j++) {
        float inv = 1.f / l_run[j];
        float* orow = out + (size_t)(r0 + j) * DIM;
#pragma unroll
        for (int n = 0; n < 16; n++)
          orow[n * 16 + lo] = o_acc[n][j] * inv;
      }
    }
  }
}

extern "C" void kernel_launch(void* const* d_in, const int* in_sizes, int n_in,
                              void* d_out, int out_size, void* d_ws, size_t ws_size,
                              hipStream_t stream) {
  const float* x  = (const float*)d_in[0];
  const float* Wq = (const float*)d_in[1];
  const float* Wk = (const float*)d_in[2];
  const float* Wv = (const float*)d_in[3];
  unsigned short* qb = (unsigned short*)d_ws;                       // 8MB
  char* kv = (char*)d_ws + (size_t)NBATCH * SEQ * DIM * 2;          // 16MB
  float* out = (float*)d_out;

  qkv_gemm<<<dim3(128, 4, 3), 256, 0, stream>>>(x, Wq, Wk, Wv, qb, kv);
  attn<<<dim3(256), 128, 0, stream>>>(qb, kv, out);
}

// Round 6
// 254.224 us; speedup vs baseline: 2.8072x; 1.0012x over previous
//
#include <hip/hip_runtime.h>
#include <hip/hip_bf16.h>

// Problem: B=4, S=4096, D=256 single-head causal attention, fp32 in/out.
// ws layout: Qb bf16 [4][4096][256] @ 0 (8MB);
//            KV @ 8MB: per (batch, kv-tile t<64) a contiguous 64KB block:
//              bytes 0..32767  : K tile, swizzled image of [64 s][512B row]:
//                                byte (r*512 + 2*d) ^ ((r&7)<<4)
//              bytes 32768..   : V tile, swizzled image of [256 d][128B row]:
//                                byte (d*128 + 2*s) ^ ((d&7)<<4)
// attn: 512 blocks (2/CU for TLP), K staged via global_load_lds (counted
// vmcnt dbuf), V read direct from the L2-resident image into VGPRs.

#define SEQ 4096
#define DIM 256
#define NBATCH 4
#define KVBLK 64
#define KVT_BYTES 65536

typedef __attribute__((ext_vector_type(8))) short bf16x8;
typedef __attribute__((ext_vector_type(4))) float f32x4;
typedef __attribute__((ext_vector_type(4))) unsigned short us4;

static __device__ inline unsigned short f2bf(float f) {
  unsigned int u = __float_as_uint(f);
  u += 0x7FFFu + ((u >> 16) & 1u);   // RNE to bf16
  return (unsigned short)(u >> 16);
}

// ---------------- Kernel 1: QKV projection, C = X @ W^T (bf16 MFMA) -----------------
// grid (M/128, 256/64, 3), block 256 (4 waves). z: 0->Q, 1->K, 2->V.
__global__ __launch_bounds__(256) void qkv_gemm(
    const float* __restrict__ x, const float* __restrict__ Wq,
    const float* __restrict__ Wk, const float* __restrict__ Wv,
    unsigned short* __restrict__ qb, char* __restrict__ kv)
{
  __shared__ unsigned short A_lds[128][40];
  __shared__ unsigned short B_lds[64][40];

  const int tid = threadIdx.x;
  const int lane = tid & 63;
  const int w = tid >> 6;
  const int lo = lane & 15, hi = lane >> 4;
  const int mb = blockIdx.x * 128;
  const int nb = blockIdx.y * 64;
  const int z = blockIdx.z;
  const float* Wm = (z == 0) ? Wq : (z == 1) ? Wk : Wv;

  f32x4 acc[2][4];
#pragma unroll
  for (int mi = 0; mi < 2; mi++)
#pragma unroll
    for (int ni = 0; ni < 4; ni++) acc[mi][ni] = (f32x4){0.f, 0.f, 0.f, 0.f};

  for (int ks = 0; ks < 8; ++ks) {
    const int k0 = ks * 32;
    __syncthreads();
#pragma unroll
    for (int i = 0; i < 4; ++i) {
      int f = tid + i * 256;
      int row = f >> 3, c4 = (f & 7) * 4;
      float4 v = *(const float4*)(x + (size_t)(mb + row) * DIM + k0 + c4);
      us4 bv = { f2bf(v.x), f2bf(v.y), f2bf(v.z), f2bf(v.w) };
      *(us4*)&A_lds[row][c4] = bv;
    }
#pragma unroll
    for (int i = 0; i < 2; ++i) {
      int f = tid + i * 256;
      int row = f >> 3, c4 = (f & 7) * 4;
      float4 v = *(const float4*)(Wm + (size_t)(nb + row) * DIM + k0 + c4);
      us4 bv = { f2bf(v.x), f2bf(v.y), f2bf(v.z), f2bf(v.w) };
      *(us4*)&B_lds[row][c4] = bv;
    }
    __syncthreads();
    bf16x8 a[2], bfr[4];
#pragma unroll
    for (int mi = 0; mi < 2; mi++) a[mi] = *(const bf16x8*)&A_lds[w * 32 + mi * 16 + lo][hi * 8];
#pragma unroll
    for (int ni = 0; ni < 4; ni++) bfr[ni] = *(const bf16x8*)&B_lds[ni * 16 + lo][hi * 8];
#pragma unroll
    for (int mi = 0; mi < 2; mi++)
#pragma unroll
      for (int ni = 0; ni < 4; ni++)
        acc[mi][ni] = __builtin_amdgcn_mfma_f32_16x16x32_bf16(a[mi], bfr[ni], acc[mi][ni], 0, 0, 0);
  }

  if (z == 0) {
#pragma unroll
    for (int mi = 0; mi < 2; mi++) {
      int r0 = mb + w * 32 + mi * 16 + hi * 4;
#pragma unroll
      for (int ni = 0; ni < 4; ni++) {
        int col = nb + ni * 16 + lo;
#pragma unroll
        for (int j = 0; j < 4; j++)
          qb[(size_t)(r0 + j) * DIM + col] = f2bf(acc[mi][ni][j]);
      }
    }
  } else if (z == 1) {
    // K: swizzled tile image, scalar 2B stores
#pragma unroll
    for (int mi = 0; mi < 2; mi++) {
      int r0 = mb + w * 32 + mi * 16 + hi * 4;
#pragma unroll
      for (int ni = 0; ni < 4; ni++) {
        int d = nb + ni * 16 + lo;
#pragma unroll
        for (int j = 0; j < 4; j++) {
          int srow = r0 + j;
          int bb = srow >> 12, sl = srow & 4095;
          int t = sl >> 6, r = sl & 63;
          size_t byte = ((size_t)(bb * 64 + t)) * KVT_BYTES +
                        (size_t)((r * 512 + 2 * d) ^ ((r & 7) << 4));
          *(unsigned short*)(kv + byte) = f2bf(acc[mi][ni][j]);
        }
      }
    }
  } else {
    // V: swizzled tile image, 8B stores (4 consecutive s per lane)
#pragma unroll
    for (int mi = 0; mi < 2; mi++) {
      int s0 = mb + w * 32 + mi * 16 + hi * 4;
      int bb = s0 >> 12, sl = s0 & 4095;
      int t = sl >> 6, sI = sl & 63;
#pragma unroll
      for (int ni = 0; ni < 4; ni++) {
        int d = nb + ni * 16 + lo;
        us4 pv = { f2bf(acc[mi][ni][0]), f2bf(acc[mi][ni][1]),
                   f2bf(acc[mi][ni][2]), f2bf(acc[mi][ni][3]) };
        size_t byte = ((size_t)(bb * 64 + t)) * KVT_BYTES + 32768 +
                      (size_t)((d * 128 + 2 * sI) ^ ((d & 7) << 4));
        *(us4*)(kv + byte) = pv;
      }
    }
  }
}

// ---------------- Kernel 2: causal flash attention -----------------
// 512 blocks (2/CU), 128 thr (2 waves). Block id: batch = id&3;
// qt = id<256 ? 127-(id>>2) : (id-256)>>2  (heavy tiles dispatched first, so
// each CU's two resident blocks sum to ~constant work). XCD x touches only
// batch x&3 (id%8 fixes id&3). K staged + counted vmcnt; V direct from L2.
__global__ __launch_bounds__(128) void attn(
    const unsigned short* __restrict__ qb, const char* __restrict__ kv,
    float* __restrict__ out)
{
  __shared__ char K_lds[2][32768];            // K tile dbuf, swizzled image
  __shared__ unsigned short P_lds[2][16][72];

  const int tid = threadIdx.x;
  const int lane = tid & 63;
  const int w = tid >> 6;
  const int lo = lane & 15, hi = lane >> 4;
  const int id = blockIdx.x;
  const int b = id & 3;
  const int qt = (id < 256) ? (127 - (id >> 2)) : ((id - 256) >> 2);
  const int qbase = qt * 32;
  const int nt = (qt >> 1) + 1;
  const float scale = 0.0625f;  // 1/sqrt(256)

  const char* kv_base = kv + (size_t)b * 64 * KVT_BYTES;
  const int rswz = (lo & 7) << 4;

  auto stageK = [&](int t, int buf) {
    const char* src = kv_base + (size_t)t * KVT_BYTES + w * 16384 + lane * 16;
    char* dst = &K_lds[buf][0] + w * 16384 + lane * 16;
#pragma unroll
    for (int i = 0; i < 16; ++i) {
      __builtin_amdgcn_global_load_lds(
          (const __attribute__((address_space(1))) void*)(src + i * 1024),
          (__attribute__((address_space(3))) void*)(dst + i * 1024),
          16, 0, 0);
    }
  };

  // Q fragments (16 rows x 256 d per wave); compiler waits their vmcnt at use
  bf16x8 qf[8];
  {
    const unsigned short* qrow = qb + (size_t)(b * SEQ + qbase + w * 16 + lo) * DIM;
#pragma unroll
    for (int kk = 0; kk < 8; kk++)
      qf[kk] = *(const bf16x8*)(qrow + kk * 32 + hi * 8);
  }

  stageK(0, 0);
  if (nt > 1) stageK(1, 1);

  float m_run[4], l_run[4];
#pragma unroll
  for (int j = 0; j < 4; j++) { m_run[j] = -__builtin_inff(); l_run[j] = 0.f; }
  f32x4 o_acc[16];
#pragma unroll
  for (int n = 0; n < 16; n++) o_acc[n] = (f32x4){0.f, 0.f, 0.f, 0.f};

  for (int t = 0; t < nt; ++t) {
    const int cur = t & 1;

    // stage(t) complete; stage(t+1) (16 loads/wave) may stay in flight
    if (t + 1 < nt) {
      asm volatile("s_waitcnt vmcnt(16)" ::: "memory");
    } else {
      asm volatile("s_waitcnt vmcnt(0)" ::: "memory");
    }
    __builtin_amdgcn_sched_barrier(0);
    __builtin_amdgcn_s_barrier();   // buffer cur ready for both waves

    // S = Q K^T   (64 kv cols: nf=0..3)
    const char* kt = &K_lds[cur][0];
    f32x4 sf[4];
#pragma unroll
    for (int nf = 0; nf < 4; nf++) {
      f32x4 a = (f32x4){0.f, 0.f, 0.f, 0.f};
#pragma unroll
      for (int kk = 0; kk < 8; kk++) {
        int byte_off = (nf * 16 + lo) * 512 + ((kk * 64 + hi * 16) ^ rswz);
        bf16x8 kfr = *(const bf16x8*)(kt + byte_off);
        a = __builtin_amdgcn_mfma_f32_16x16x32_bf16(qf[kk], kfr, a, 0, 0, 0);
      }
      sf[nf] = a;
    }

    // scale + causal mask (only the last tile can touch the diagonal)
    const bool diag = (t == nt - 1);
    float s[4][4];
#pragma unroll
    for (int nf = 0; nf < 4; nf++)
#pragma unroll
      for (int j = 0; j < 4; j++) {
        float v = sf[nf][j] * scale;
        if (diag) {
          int qg = qbase + w * 16 + hi * 4 + j;
          int kg = t * KVBLK + nf * 16 + lo;
          if (kg > qg) v = -__builtin_inff();
        }
        s[nf][j] = v;
      }

    // online softmax with defer-max (T13)
    float vnew[4];
#pragma unroll
    for (int j = 0; j < 4; j++) {
      float v = fmaxf(fmaxf(s[0][j], s[1][j]), fmaxf(s[2][j], s[3][j]));
      v = fmaxf(v, __shfl_xor(v, 1));
      v = fmaxf(v, __shfl_xor(v, 2));
      v = fmaxf(v, __shfl_xor(v, 4));
      v = fmaxf(v, __shfl_xor(v, 8));
      vnew[j] = v;
    }
    bool grow = false;
#pragma unroll
    for (int j = 0; j < 4; j++) grow = grow || (vnew[j] > m_run[j] + 8.f);
    if (__any(grow)) {
#pragma unroll
      for (int j = 0; j < 4; j++) {
        float mn = fmaxf(m_run[j], vnew[j]);
        float alpha = __expf(m_run[j] - mn);
        m_run[j] = mn;
        l_run[j] *= alpha;
#pragma unroll
        for (int n = 0; n < 16; n++) o_acc[n][j] *= alpha;
      }
    }
    float pr[4][4];
#pragma unroll
    for (int j = 0; j < 4; j++) {
      float sum = 0.f;
#pragma unroll
      for (int nf = 0; nf < 4; nf++) {
        pr[nf][j] = __expf(s[nf][j] - m_run[j]);
        sum += pr[nf][j];
      }
      sum += __shfl_xor(sum, 1);
      sum += __shfl_xor(sum, 2);
      sum += __shfl_xor(sum, 4);
      sum += __shfl_xor(sum, 8);
      l_run[j] += sum;
    }

    // P -> per-wave LDS (bf16), read back as two A-fragments (k 0..31, 32..63)
#pragma unroll
    for (int nf = 0; nf < 4; nf++)
#pragma unroll
      for (int j = 0; j < 4; j++)
        P_lds[w][hi * 4 + j][nf * 16 + lo] = f2bf(pr[nf][j]);

    bf16x8 pa0 = *(const bf16x8*)&P_lds[w][lo][hi * 8];
    bf16x8 pa1 = *(const bf16x8*)&P_lds[w][lo][32 + hi * 8];

    // O += P V  — V direct from the L2-resident swizzled tile image,
    // grouped 4 n at a time (8 loads in flight) for MLP.
    const char* vglob = kv_base + (size_t)t * KVT_BYTES + 32768;
#pragma unroll
    for (int g = 0; g < 4; g++) {
      bf16x8 va[4], vb[4];
#pragma unroll
      for (int k = 0; k < 4; k++) {
        int rowb = ((g * 4 + k) * 16 + lo) * 128;
        va[k] = *(const bf16x8*)(vglob + rowb + ((hi * 16) ^ rswz));
        vb[k] = *(const bf16x8*)(vglob + rowb + ((64 + hi * 16) ^ rswz));
      }
#pragma unroll
      for (int k = 0; k < 4; k++) {
        o_acc[g * 4 + k] = __builtin_amdgcn_mfma_f32_16x16x32_bf16(pa0, va[k], o_acc[g * 4 + k], 0, 0, 0);
        o_acc[g * 4 + k] = __builtin_amdgcn_mfma_f32_16x16x32_bf16(pa1, vb[k], o_acc[g * 4 + k], 0, 0, 0);
      }
    }

    __builtin_amdgcn_sched_barrier(0);
    __builtin_amdgcn_s_barrier();   // both waves done reading K_lds[cur]
    if (t + 2 < nt) stageK(t + 2, cur);   // overwrite freed buffer
  }

  // epilogue: out = O / l
  {
    int r0 = b * SEQ + qbase + w * 16 + hi * 4;
#pragma unroll
    for (int j = 0; j < 4; j++) {
      float inv = 1.f / l_run[j];
      float* orow = out + (size_t)(r0 + j) * DIM;
#pragma unroll
      for (int n = 0; n < 16; n++)
        orow[n * 16 + lo] = o_acc[n][j] * inv;
    }
  }
}

extern "C" void kernel_launch(void* const* d_in, const int* in_sizes, int n_in,
                              void* d_out, int out_size, void* d_ws, size_t ws_size,
                              hipStream_t stream) {
  const float* x  = (const float*)d_in[0];
  const float* Wq = (const float*)d_in[1];
  const float* Wk = (const float*)d_in[2];
  const float* Wv = (const float*)d_in[3];
  unsigned short* qb = (unsigned short*)d_ws;                       // 8MB
  char* kv = (char*)d_ws + (size_t)NBATCH * SEQ * DIM * 2;          // 16MB
  float* out = (float*)d_out;

  qkv_gemm<<<dim3(128, 4, 3), 256, 0, stream>>>(x, Wq, Wk, Wv, qb, kv);
  attn<<<dim3(512), 128, 0, stream>>>(qb, kv, out);
}

// Round 7
// 214.678 us; speedup vs baseline: 3.3243x; 1.1842x over previous
//
#include <hip/hip_runtime.h>
#include <hip/hip_bf16.h>

// Problem: B=4, S=4096, D=256 single-head causal attention, fp32 in/out.
// ws: Qb bf16 [4][4096][256] @0 (8MB)
//     KV @8MB: per (batch, kv-tile t<64) 64KB block:
//        [0..32K):  K swizzled image, byte (r*512 + 2*d) ^ ((r&7)<<4)
//        [32K..64K):V swizzled image, byte (d*128 + 2*s) ^ ((d&7)<<4)
//     O1 bf16 [16384][256] @24MB (8MB)   (chunk1 normalized partial)
//     ml0 fp32 [16384][2] @32MB, ml1 @32.125MB
// attn: flash-decoding. 2048 one-wave blocks; (batch,qt 0..255,chunk 0/1);
// no LDS staging, no barriers; K/V direct from L2-resident swizzled image.

#define SEQ 4096
#define DIM 256
#define NBATCH 4
#define KVBLK 64
#define KVT_BYTES 65536

#define QB_OFF   0
#define KV_OFF   (8u*1024*1024)
#define O1_OFF   (24u*1024*1024)
#define ML0_OFF  (32u*1024*1024)
#define ML1_OFF  (ML0_OFF + 16384u*2*4)
#define WS_NEED  (ML1_OFF + 16384u*2*4)

typedef __attribute__((ext_vector_type(8))) short bf16x8;
typedef __attribute__((ext_vector_type(4))) float f32x4;
typedef __attribute__((ext_vector_type(4))) unsigned short us4;

static __device__ inline unsigned short f2bf(float f) {
  unsigned int u = __float_as_uint(f);
  u += 0x7FFFu + ((u >> 16) & 1u);
  return (unsigned short)(u >> 16);
}
static __device__ inline float bf2f(unsigned short u) {
  return __uint_as_float(((unsigned int)u) << 16);
}

// ---------------- Kernel 1: QKV projection (unchanged) -----------------
__global__ __launch_bounds__(256) void qkv_gemm(
    const float* __restrict__ x, const float* __restrict__ Wq,
    const float* __restrict__ Wk, const float* __restrict__ Wv,
    unsigned short* __restrict__ qb, char* __restrict__ kv)
{
  __shared__ unsigned short A_lds[128][40];
  __shared__ unsigned short B_lds[64][40];

  const int tid = threadIdx.x;
  const int lane = tid & 63;
  const int w = tid >> 6;
  const int lo = lane & 15, hi = lane >> 4;
  const int mb = blockIdx.x * 128;
  const int nb = blockIdx.y * 64;
  const int z = blockIdx.z;
  const float* Wm = (z == 0) ? Wq : (z == 1) ? Wk : Wv;

  f32x4 acc[2][4];
#pragma unroll
  for (int mi = 0; mi < 2; mi++)
#pragma unroll
    for (int ni = 0; ni < 4; ni++) acc[mi][ni] = (f32x4){0.f, 0.f, 0.f, 0.f};

  for (int ks = 0; ks < 8; ++ks) {
    const int k0 = ks * 32;
    __syncthreads();
#pragma unroll
    for (int i = 0; i < 4; ++i) {
      int f = tid + i * 256;
      int row = f >> 3, c4 = (f & 7) * 4;
      float4 v = *(const float4*)(x + (size_t)(mb + row) * DIM + k0 + c4);
      us4 bv = { f2bf(v.x), f2bf(v.y), f2bf(v.z), f2bf(v.w) };
      *(us4*)&A_lds[row][c4] = bv;
    }
#pragma unroll
    for (int i = 0; i < 2; ++i) {
      int f = tid + i * 256;
      int row = f >> 3, c4 = (f & 7) * 4;
      float4 v = *(const float4*)(Wm + (size_t)(nb + row) * DIM + k0 + c4);
      us4 bv = { f2bf(v.x), f2bf(v.y), f2bf(v.z), f2bf(v.w) };
      *(us4*)&B_lds[row][c4] = bv;
    }
    __syncthreads();
    bf16x8 a[2], bfr[4];
#pragma unroll
    for (int mi = 0; mi < 2; mi++) a[mi] = *(const bf16x8*)&A_lds[w * 32 + mi * 16 + lo][hi * 8];
#pragma unroll
    for (int ni = 0; ni < 4; ni++) bfr[ni] = *(const bf16x8*)&B_lds[ni * 16 + lo][hi * 8];
#pragma unroll
    for (int mi = 0; mi < 2; mi++)
#pragma unroll
      for (int ni = 0; ni < 4; ni++)
        acc[mi][ni] = __builtin_amdgcn_mfma_f32_16x16x32_bf16(a[mi], bfr[ni], acc[mi][ni], 0, 0, 0);
  }

  if (z == 0) {
#pragma unroll
    for (int mi = 0; mi < 2; mi++) {
      int r0 = mb + w * 32 + mi * 16 + hi * 4;
#pragma unroll
      for (int ni = 0; ni < 4; ni++) {
        int col = nb + ni * 16 + lo;
#pragma unroll
        for (int j = 0; j < 4; j++)
          qb[(size_t)(r0 + j) * DIM + col] = f2bf(acc[mi][ni][j]);
      }
    }
  } else if (z == 1) {
#pragma unroll
    for (int mi = 0; mi < 2; mi++) {
      int r0 = mb + w * 32 + mi * 16 + hi * 4;
#pragma unroll
      for (int ni = 0; ni < 4; ni++) {
        int d = nb + ni * 16 + lo;
#pragma unroll
        for (int j = 0; j < 4; j++) {
          int srow = r0 + j;
          int bb = srow >> 12, sl = srow & 4095;
          int t = sl >> 6, r = sl & 63;
          size_t byte = ((size_t)(bb * 64 + t)) * KVT_BYTES +
                        (size_t)((r * 512 + 2 * d) ^ ((r & 7) << 4));
          *(unsigned short*)(kv + byte) = f2bf(acc[mi][ni][j]);
        }
      }
    }
  } else {
#pragma unroll
    for (int mi = 0; mi < 2; mi++) {
      int s0 = mb + w * 32 + mi * 16 + hi * 4;
      int bb = s0 >> 12, sl = s0 & 4095;
      int t = sl >> 6, sI = sl & 63;
#pragma unroll
      for (int ni = 0; ni < 4; ni++) {
        int d = nb + ni * 16 + lo;
        us4 pv = { f2bf(acc[mi][ni][0]), f2bf(acc[mi][ni][1]),
                   f2bf(acc[mi][ni][2]), f2bf(acc[mi][ni][3]) };
        size_t byte = ((size_t)(bb * 64 + t)) * KVT_BYTES + 32768 +
                      (size_t)((d * 128 + 2 * sI) ^ ((d & 7) << 4));
        *(us4*)(kv + byte) = pv;
      }
    }
  }
}

// ---------------- Kernel 2a: flash-decoding attention (split-2) -----------------
// 2048 blocks x 64 thr (1 wave each, fully autonomous). id&7 = XCD slot:
// batch = (id&7)>>1, chunk = id&1; v=(id>>3) -> qt via alternating heavy/light.
__global__ __launch_bounds__(64, 2) void attn_split(
    const unsigned short* __restrict__ qb, const char* __restrict__ kv,
    float* __restrict__ out, unsigned short* __restrict__ o1,
    float* __restrict__ ml0, float* __restrict__ ml1)
{
  __shared__ unsigned short P_lds[16][72];

  const int lane = threadIdx.x & 63;
  const int lo = lane & 15, hi = lane >> 4;
  const int id = blockIdx.x;
  const int x = id & 7;
  const int b = x >> 1;
  const int c = x & 1;                      // chunk
  const int v = id >> 3;                    // 0..255
  const int qt = (v & 1) ? (255 - (v >> 1)) : (v >> 1);
  const int nt = (qt >> 2) + 1;
  const int h = (nt + 1) >> 1;
  const int t0 = c ? h : 0;
  const int t1 = c ? nt : h;
  const float scale = 0.0625f;

  const int rbase = b * SEQ + qt * 16;      // global row of this q-tile
  if (t0 >= t1) {
    // empty chunk1 (qt<4): record zero weight
    if (lane < 4 && c) {
      ml1[(size_t)(rbase + lane * 4 + 0) * 2 + 0] = -1e30f;  // placeholder; fixed below
    }
    // write all 16 rows' (m,l)
    if (lane < 16) {
      ml1[(size_t)(rbase + lane) * 2 + 0] = -1e30f;
      ml1[(size_t)(rbase + lane) * 2 + 1] = 0.f;
    }
    return;
  }

  const char* kv_base = kv + (size_t)b * 64 * KVT_BYTES;
  const int rswz = (lo & 7) << 4;

  bf16x8 qf[8];
  {
    const unsigned short* qrow = qb + (size_t)(rbase + lo) * DIM;
#pragma unroll
    for (int kk = 0; kk < 8; kk++)
      qf[kk] = *(const bf16x8*)(qrow + kk * 32 + hi * 8);
  }

  float m_run[4], l_run[4];
#pragma unroll
  for (int j = 0; j < 4; j++) { m_run[j] = -__builtin_inff(); l_run[j] = 0.f; }
  f32x4 o_acc[16];
#pragma unroll
  for (int n = 0; n < 16; n++) o_acc[n] = (f32x4){0.f, 0.f, 0.f, 0.f};

  for (int t = t0; t < t1; ++t) {
    const char* tileb = kv_base + (size_t)t * KVT_BYTES;

    // S = Q K^T, K direct from L2-resident swizzled image (8 loads in flight/nf)
    f32x4 sf[4];
#pragma unroll
    for (int nf = 0; nf < 4; nf++) {
      const char* kbase = tileb + (nf * 16 + lo) * 512;
      bf16x8 kf[8];
#pragma unroll
      for (int kk = 0; kk < 8; kk++)
        kf[kk] = *(const bf16x8*)(kbase + ((kk * 64 + hi * 16) ^ rswz));
      f32x4 a = (f32x4){0.f, 0.f, 0.f, 0.f};
#pragma unroll
      for (int kk = 0; kk < 8; kk++)
        a = __builtin_amdgcn_mfma_f32_16x16x32_bf16(qf[kk], kf[kk], a, 0, 0, 0);
      sf[nf] = a;
    }

    const bool diag = (t == nt - 1);
    float s[4][4];
#pragma unroll
    for (int nf = 0; nf < 4; nf++)
#pragma unroll
      for (int j = 0; j < 4; j++) {
        float vv = sf[nf][j] * scale;
        if (diag) {
          int qg = qt * 16 + hi * 4 + j;
          int kg = t * KVBLK + nf * 16 + lo;
          if (kg > qg) vv = -__builtin_inff();
        }
        s[nf][j] = vv;
      }

    // online softmax with defer-max
    float vnew[4];
#pragma unroll
    for (int j = 0; j < 4; j++) {
      float m = fmaxf(fmaxf(s[0][j], s[1][j]), fmaxf(s[2][j], s[3][j]));
      m = fmaxf(m, __shfl_xor(m, 1));
      m = fmaxf(m, __shfl_xor(m, 2));
      m = fmaxf(m, __shfl_xor(m, 4));
      m = fmaxf(m, __shfl_xor(m, 8));
      vnew[j] = m;
    }
    bool grow = false;
#pragma unroll
    for (int j = 0; j < 4; j++) grow = grow || (vnew[j] > m_run[j] + 8.f);
    if (__any(grow)) {
#pragma unroll
      for (int j = 0; j < 4; j++) {
        float mn = fmaxf(m_run[j], vnew[j]);
        float alpha = __expf(m_run[j] - mn);
        m_run[j] = mn;
        l_run[j] *= alpha;
#pragma unroll
        for (int n = 0; n < 16; n++) o_acc[n][j] *= alpha;
      }
    }
    float pr[4][4];
#pragma unroll
    for (int j = 0; j < 4; j++) {
      float sum = 0.f;
#pragma unroll
      for (int nf = 0; nf < 4; nf++) {
        pr[nf][j] = __expf(s[nf][j] - m_run[j]);
        sum += pr[nf][j];
      }
      sum += __shfl_xor(sum, 1);
      sum += __shfl_xor(sum, 2);
      sum += __shfl_xor(sum, 4);
      sum += __shfl_xor(sum, 8);
      l_run[j] += sum;
    }

    // P -> LDS roundtrip (wave-local)
#pragma unroll
    for (int nf = 0; nf < 4; nf++)
#pragma unroll
      for (int j = 0; j < 4; j++)
        P_lds[hi * 4 + j][nf * 16 + lo] = f2bf(pr[nf][j]);

    bf16x8 pa0 = *(const bf16x8*)&P_lds[lo][hi * 8];
    bf16x8 pa1 = *(const bf16x8*)&P_lds[lo][32 + hi * 8];

    // O += P V  (V direct from L2-resident swizzled image)
    const char* vglob = tileb + 32768;
#pragma unroll
    for (int g = 0; g < 4; g++) {
      bf16x8 va[4], vb[4];
#pragma unroll
      for (int k = 0; k < 4; k++) {
        int rowb = ((g * 4 + k) * 16 + lo) * 128;
        va[k] = *(const bf16x8*)(vglob + rowb + ((hi * 16) ^ rswz));
        vb[k] = *(const bf16x8*)(vglob + rowb + ((64 + hi * 16) ^ rswz));
      }
#pragma unroll
      for (int k = 0; k < 4; k++) {
        o_acc[g * 4 + k] = __builtin_amdgcn_mfma_f32_16x16x32_bf16(pa0, va[k], o_acc[g * 4 + k], 0, 0, 0);
        o_acc[g * 4 + k] = __builtin_amdgcn_mfma_f32_16x16x32_bf16(pa1, vb[k], o_acc[g * 4 + k], 0, 0, 0);
      }
    }
  }

  // epilogue: normalized partial + (m,l)
  if (c == 0) {
#pragma unroll
    for (int j = 0; j < 4; j++) {
      int r = rbase + hi * 4 + j;
      float inv = 1.f / l_run[j];
      float* orow = out + (size_t)r * DIM;
#pragma unroll
      for (int n = 0; n < 16; n++)
        orow[n * 16 + lo] = o_acc[n][j] * inv;
    }
    if (lane < 16) {   // one lane per row writes (m,l): row lane -> j=lane&3? need per-row value
    }
    // (m,l) per row: lanes with lo==0 hold reduced values for rows hi*4+j
    if (lo == 0) {
#pragma unroll
      for (int j = 0; j < 4; j++) {
        int r = rbase + hi * 4 + j;
        ml0[(size_t)r * 2 + 0] = m_run[j];
        ml0[(size_t)r * 2 + 1] = l_run[j];
      }
    }
  } else {
#pragma unroll
    for (int j = 0; j < 4; j++) {
      int r = rbase + hi * 4 + j;
      float inv = 1.f / l_run[j];
      unsigned short* orow = o1 + (size_t)r * DIM;
#pragma unroll
      for (int n = 0; n < 16; n++)
        orow[n * 16 + lo] = f2bf(o_acc[n][j] * inv);
    }
    if (lo == 0) {
#pragma unroll
      for (int j = 0; j < 4; j++) {
        int r = rbase + hi * 4 + j;
        ml1[(size_t)r * 2 + 0] = m_run[j];
        ml1[(size_t)r * 2 + 1] = l_run[j];
      }
    }
  }
}

// ---------------- Kernel 2b: merge partials -----------------
// out = (w0*O0 + w1*O1)/(w0+w1), w_i = l_i*exp(m_i-M). grid 4096 x 256 thr.
__global__ __launch_bounds__(256) void merge_k(
    const float* __restrict__ ml0, const float* __restrict__ ml1,
    const unsigned short* __restrict__ o1, float* __restrict__ out)
{
  int r = blockIdx.x * 4 + (threadIdx.x >> 6);
  int c4 = (threadIdx.x & 63) * 4;
  float m0 = ml0[(size_t)r * 2 + 0], l0 = ml0[(size_t)r * 2 + 1];
  float m1 = ml1[(size_t)r * 2 + 0], l1 = ml1[(size_t)r * 2 + 1];
  float M = fmaxf(m0, m1);
  float w0 = l0 * __expf(m0 - M);
  float w1 = l1 * __expf(m1 - M);
  float inv = 1.f / (w0 + w1);
  float4 o0 = *(const float4*)(out + (size_t)r * DIM + c4);
  us4 ov = *(const us4*)(o1 + (size_t)r * DIM + c4);
  float4 res;
  res.x = (w0 * o0.x + w1 * bf2f(ov.x)) * inv;
  res.y = (w0 * o0.y + w1 * bf2f(ov.y)) * inv;
  res.z = (w0 * o0.z + w1 * bf2f(ov.z)) * inv;
  res.w = (w0 * o0.w + w1 * bf2f(ov.w)) * inv;
  *(float4*)(out + (size_t)r * DIM + c4) = res;
}

// ---------------- Fallback (R6 attn, unchanged) -----------------
__global__ __launch_bounds__(128) void attn_fb(
    const unsigned short* __restrict__ qb, const char* __restrict__ kv,
    float* __restrict__ out)
{
  __shared__ char K_lds[2][32768];
  __shared__ unsigned short P_lds[2][16][72];

  const int tid = threadIdx.x;
  const int lane = tid & 63;
  const int w = tid >> 6;
  const int lo = lane & 15, hi = lane >> 4;
  const int id = blockIdx.x;
  const int b = id & 3;
  const int qt = (id < 256) ? (127 - (id >> 2)) : ((id - 256) >> 2);
  const int qbase = qt * 32;
  const int nt = (qt >> 1) + 1;
  const float scale = 0.0625f;

  const char* kv_base = kv + (size_t)b * 64 * KVT_BYTES;
  const int rswz = (lo & 7) << 4;

  auto stageK = [&](int t, int buf) {
    const char* src = kv_base + (size_t)t * KVT_BYTES + w * 16384 + lane * 16;
    char* dst = &K_lds[buf][0] + w * 16384 + lane * 16;
#pragma unroll
    for (int i = 0; i < 16; ++i) {
      __builtin_amdgcn_global_load_lds(
          (const __attribute__((address_space(1))) void*)(src + i * 1024),
          (__attribute__((address_space(3))) void*)(dst + i * 1024),
          16, 0, 0);
    }
  };

  bf16x8 qf[8];
  {
    const unsigned short* qrow = qb + (size_t)(b * SEQ + qbase + w * 16 + lo) * DIM;
#pragma unroll
    for (int kk = 0; kk < 8; kk++)
      qf[kk] = *(const bf16x8*)(qrow + kk * 32 + hi * 8);
  }

  stageK(0, 0);
  if (nt > 1) stageK(1, 1);

  float m_run[4], l_run[4];
#pragma unroll
  for (int j = 0; j < 4; j++) { m_run[j] = -__builtin_inff(); l_run[j] = 0.f; }
  f32x4 o_acc[16];
#pragma unroll
  for (int n = 0; n < 16; n++) o_acc[n] = (f32x4){0.f, 0.f, 0.f, 0.f};

  for (int t = 0; t < nt; ++t) {
    const int cur = t & 1;
    if (t + 1 < nt) {
      asm volatile("s_waitcnt vmcnt(16)" ::: "memory");
    } else {
      asm volatile("s_waitcnt vmcnt(0)" ::: "memory");
    }
    __builtin_amdgcn_sched_barrier(0);
    __builtin_amdgcn_s_barrier();

    const char* kt = &K_lds[cur][0];
    f32x4 sf[4];
#pragma unroll
    for (int nf = 0; nf < 4; nf++) {
      f32x4 a = (f32x4){0.f, 0.f, 0.f, 0.f};
#pragma unroll
      for (int kk = 0; kk < 8; kk++) {
        int byte_off = (nf * 16 + lo) * 512 + ((kk * 64 + hi * 16) ^ rswz);
        bf16x8 kfr = *(const bf16x8*)(kt + byte_off);
        a = __builtin_amdgcn_mfma_f32_16x16x32_bf16(qf[kk], kfr, a, 0, 0, 0);
      }
      sf[nf] = a;
    }

    const bool diag = (t == nt - 1);
    float s[4][4];
#pragma unroll
    for (int nf = 0; nf < 4; nf++)
#pragma unroll
      for (int j = 0; j < 4; j++) {
        float vv = sf[nf][j] * scale;
        if (diag) {
          int qg = qbase + w * 16 + hi * 4 + j;
          int kg = t * KVBLK + nf * 16 + lo;
          if (kg > qg) vv = -__builtin_inff();
        }
        s[nf][j] = vv;
      }

    float vnew[4];
#pragma unroll
    for (int j = 0; j < 4; j++) {
      float m = fmaxf(fmaxf(s[0][j], s[1][j]), fmaxf(s[2][j], s[3][j]));
      m = fmaxf(m, __shfl_xor(m, 1));
      m = fmaxf(m, __shfl_xor(m, 2));
      m = fmaxf(m, __shfl_xor(m, 4));
      m = fmaxf(m, __shfl_xor(m, 8));
      vnew[j] = m;
    }
    bool grow = false;
#pragma unroll
    for (int j = 0; j < 4; j++) grow = grow || (vnew[j] > m_run[j] + 8.f);
    if (__any(grow)) {
#pragma unroll
      for (int j = 0; j < 4; j++) {
        float mn = fmaxf(m_run[j], vnew[j]);
        float alpha = __expf(m_run[j] - mn);
        m_run[j] = mn;
        l_run[j] *= alpha;
#pragma unroll
        for (int n = 0; n < 16; n++) o_acc[n][j] *= alpha;
      }
    }
    float pr[4][4];
#pragma unroll
    for (int j = 0; j < 4; j++) {
      float sum = 0.f;
#pragma unroll
      for (int nf = 0; nf < 4; nf++) {
        pr[nf][j] = __expf(s[nf][j] - m_run[j]);
        sum += pr[nf][j];
      }
      sum += __shfl_xor(sum, 1);
      sum += __shfl_xor(sum, 2);
      sum += __shfl_xor(sum, 4);
      sum += __shfl_xor(sum, 8);
      l_run[j] += sum;
    }

#pragma unroll
    for (int nf = 0; nf < 4; nf++)
#pragma unroll
      for (int j = 0; j < 4; j++)
        P_lds[w][hi * 4 + j][nf * 16 + lo] = f2bf(pr[nf][j]);

    bf16x8 pa0 = *(const bf16x8*)&P_lds[w][lo][hi * 8];
    bf16x8 pa1 = *(const bf16x8*)&P_lds[w][lo][32 + hi * 8];

    const char* vglob = kv_base + (size_t)t * KVT_BYTES + 32768;
#pragma unroll
    for (int g = 0; g < 4; g++) {
      bf16x8 va[4], vb[4];
#pragma unroll
      for (int k = 0; k < 4; k++) {
        int rowb = ((g * 4 + k) * 16 + lo) * 128;
        va[k] = *(const bf16x8*)(vglob + rowb + ((hi * 16) ^ rswz));
        vb[k] = *(const bf16x8*)(vglob + rowb + ((64 + hi * 16) ^ rswz));
      }
#pragma unroll
      for (int k = 0; k < 4; k++) {
        o_acc[g * 4 + k] = __builtin_amdgcn_mfma_f32_16x16x32_bf16(pa0, va[k], o_acc[g * 4 + k], 0, 0, 0);
        o_acc[g * 4 + k] = __builtin_amdgcn_mfma_f32_16x16x32_bf16(pa1, vb[k], o_acc[g * 4 + k], 0, 0, 0);
      }
    }

    __builtin_amdgcn_sched_barrier(0);
    __builtin_amdgcn_s_barrier();
    if (t + 2 < nt) stageK(t + 2, cur);
  }

  {
    int r0 = b * SEQ + qbase + w * 16 + hi * 4;
#pragma unroll
    for (int j = 0; j < 4; j++) {
      float inv = 1.f / l_run[j];
      float* orow = out + (size_t)(r0 + j) * DIM;
#pragma unroll
      for (int n = 0; n < 16; n++)
        orow[n * 16 + lo] = o_acc[n][j] * inv;
    }
  }
}

extern "C" void kernel_launch(void* const* d_in, const int* in_sizes, int n_in,
                              void* d_out, int out_size, void* d_ws, size_t ws_size,
                              hipStream_t stream) {
  const float* x  = (const float*)d_in[0];
  const float* Wq = (const float*)d_in[1];
  const float* Wk = (const float*)d_in[2];
  const float* Wv = (const float*)d_in[3];
  char* ws = (char*)d_ws;
  unsigned short* qb = (unsigned short*)(ws + QB_OFF);
  char* kv = ws + KV_OFF;
  float* out = (float*)d_out;

  qkv_gemm<<<dim3(128, 4, 3), 256, 0, stream>>>(x, Wq, Wk, Wv, qb, kv);

  if (ws_size >= (size_t)WS_NEED) {
    unsigned short* o1 = (unsigned short*)(ws + O1_OFF);
    float* ml0 = (float*)(ws + ML0_OFF);
    float* ml1 = (float*)(ws + ML1_OFF);
    attn_split<<<dim3(2048), 64, 0, stream>>>(qb, kv, out, o1, ml0, ml1);
    merge_k<<<dim3(4096), 256, 0, stream>>>(ml0, ml1, o1, out);
  } else {
    attn_fb<<<dim3(512), 128, 0, stream>>>(qb, kv, out);
  }
}